// Round 1
// baseline (4510.321 us; speedup 1.0000x reference)
//
#include <hip/hip_runtime.h>
#include <hip/hip_bf16.h>
#include <math.h>

// Problem constants
#define B_   16
#define S_   1024
#define D_   256
#define H_   8
#define HD_  32
#define L_   6
#define H2_  1024
#define LN_EPS 1e-5f
#define SCALE_ 0.17677669529663687f  // 1/sqrt(32)

// ---------------------------------------------------------------------------
// Embedding: x[b,s,d] = iw*emb_table[tok][d] + pw*pos_emb(s,d)
// pos_emb(p,d) = d<128 ? sin(p*invf(d)) : cos(p*invf(d-128)),
// invf(j) = 10000^(-j/128) = exp2(-j/128 * log2(10000))
// ---------------------------------------------------------------------------
__global__ __launch_bounds__(256) void embed_kernel(
    const int* __restrict__ tokens, const int* __restrict__ pos_ids,
    const float* __restrict__ emb, const float* __restrict__ iwp,
    const float* __restrict__ pwp, float* __restrict__ X)
{
    int bs = blockIdx.x;            // 0..16383
    int s = bs & (S_ - 1);
    int d = threadIdx.x;            // 0..255
    int tok = tokens[bs];
    float p = (float)pos_ids[s];
    int j = (d < 128) ? d : (d - 128);
    float invf = exp2f(-(float)j * (13.287712379549449f / 128.0f));
    float ang = p * invf;
    float pe = (d < 128) ? sinf(ang) : cosf(ang);
    X[(size_t)bs * D_ + d] = iwp[0] * emb[tok * D_ + d] + pwp[0] * pe;
}

// ---------------------------------------------------------------------------
// LayerNorm: one 64-lane wave per row of 256 floats (float4 per lane).
// blockDim=256 (4 waves -> 4 rows per block). Works in-place.
// ---------------------------------------------------------------------------
__global__ __launch_bounds__(256) void ln_kernel(
    const float* __restrict__ X, const float* __restrict__ w,
    const float* __restrict__ b, float* __restrict__ out)
{
    int row = blockIdx.x * 4 + (threadIdx.x >> 6);
    int lane = threadIdx.x & 63;
    const float4 v = *(const float4*)(X + (size_t)row * D_ + lane * 4);
    float s = v.x + v.y + v.z + v.w;
    #pragma unroll
    for (int m = 1; m < 64; m <<= 1) s += __shfl_xor(s, m, 64);
    float mu = s * (1.0f / 256.0f);
    float dx = v.x - mu, dy = v.y - mu, dz = v.z - mu, dw = v.w - mu;
    float vs = dx * dx + dy * dy + dz * dz + dw * dw;
    #pragma unroll
    for (int m = 1; m < 64; m <<= 1) vs += __shfl_xor(vs, m, 64);
    float inv = rsqrtf(vs * (1.0f / 256.0f) + LN_EPS);
    float4 wv = *(const float4*)(w + lane * 4);
    float4 bv = *(const float4*)(b + lane * 4);
    float4 o;
    o.x = dx * inv * wv.x + bv.x;
    o.y = dy * inv * wv.y + bv.y;
    o.z = dz * inv * wv.z + bv.z;
    o.w = dw * inv * wv.w + bv.w;
    *(float4*)(out + (size_t)row * D_ + lane * 4) = o;
}

// ---------------------------------------------------------------------------
// Flash attention, f32, q=k=v=xn head slices. Block: 256 threads, 32 queries.
// thread role: q = tid>>3 (0..31), j = tid&7; thread owns O[q][j*4..j*4+3].
// Q row kept in registers; K/V tile (same data) staged in LDS.
// bias(h,qg,tg) = (tg>qg ? -2^-(0.5+h) : -2^-(1+h)) * manhattan(qg,tg)
// Adds result into X (residual).
// grid: (S/32, B*H)
// ---------------------------------------------------------------------------
__global__ __launch_bounds__(256) void attn_kernel(
    const float* __restrict__ XN, float* __restrict__ X)
{
    __shared__ float Ks[32][36];
    __shared__ float Ps[32][33];
    int bh = blockIdx.y;
    int b = bh >> 3, h = bh & 7;
    int qbase = blockIdx.x * 32;
    int tid = threadIdx.x;
    int q = tid >> 3, j = tid & 7;
    int li = tid >> 3, lc = (tid & 7) * 4;   // tile-load role: row li, col lc..lc+3
    int d0 = j * 4;
    int qg = qbase + q;
    int rq = qg >> 5, cq = qg & 31;
    float slope_r = -exp2f(-(0.5f + (float)h));
    float slope_l = -exp2f(-(1.0f + (float)h));

    // Q row into registers (32 floats)
    float qv[32];
    const float* qrow = XN + ((size_t)(b * S_ + qg)) * D_ + h * HD_;
    #pragma unroll
    for (int c0 = 0; c0 < 32; c0 += 4) {
        float4 t = *(const float4*)(qrow + c0);
        qv[c0] = t.x; qv[c0 + 1] = t.y; qv[c0 + 2] = t.z; qv[c0 + 3] = t.w;
    }

    float m = -1e30f, lsum = 0.0f;
    float o[4] = {0.f, 0.f, 0.f, 0.f};

    for (int kt = 0; kt < 32; kt++) {
        __syncthreads();   // previous PV finished reading Ks
        *(float4*)(&Ks[li][lc]) =
            *(const float4*)(XN + ((size_t)(b * S_ + kt * 32 + li)) * D_ + h * HD_ + lc);
        __syncthreads();   // Ks ready

        float sc[4];
        float tmax = -1e30f;
        #pragma unroll
        for (int kk = 0; kk < 4; kk++) {
            int tl = j + kk * 8;
            int tg = kt * 32 + tl;
            float acc = 0.0f;
            #pragma unroll
            for (int c0 = 0; c0 < 32; c0 += 4) {
                float4 kv = *(const float4*)(&Ks[tl][c0]);
                acc += qv[c0] * kv.x + qv[c0 + 1] * kv.y
                     + qv[c0 + 2] * kv.z + qv[c0 + 3] * kv.w;
            }
            int rt = tg >> 5, ct = tg & 31;
            int dr = rq - rt; dr = dr < 0 ? -dr : dr;
            int dc = cq - ct; dc = dc < 0 ? -dc : dc;
            float dist = (float)(dr + dc);
            float slope = (tg > qg) ? slope_r : slope_l;
            float sv = acc * SCALE_ + slope * dist;
            sc[kk] = sv;
            tmax = fmaxf(tmax, sv);
        }
        tmax = fmaxf(tmax, __shfl_xor(tmax, 1, 8));
        tmax = fmaxf(tmax, __shfl_xor(tmax, 2, 8));
        tmax = fmaxf(tmax, __shfl_xor(tmax, 4, 8));
        float mnew = fmaxf(m, tmax);
        float psum = 0.0f;
        #pragma unroll
        for (int kk = 0; kk < 4; kk++) {
            float p = __expf(sc[kk] - mnew);
            psum += p;
            Ps[q][j + kk * 8] = p;
        }
        psum += __shfl_xor(psum, 1, 8);
        psum += __shfl_xor(psum, 2, 8);
        psum += __shfl_xor(psum, 4, 8);
        float alpha = __expf(m - mnew);
        lsum = lsum * alpha + psum;
        m = mnew;
        o[0] *= alpha; o[1] *= alpha; o[2] *= alpha; o[3] *= alpha;
        __syncthreads();   // Ps ready
        #pragma unroll
        for (int t = 0; t < 32; t++) {
            float p = Ps[q][t];
            o[0] += p * Ks[t][d0 + 0];
            o[1] += p * Ks[t][d0 + 1];
            o[2] += p * Ks[t][d0 + 2];
            o[3] += p * Ks[t][d0 + 3];
        }
    }
    float inv = 1.0f / lsum;
    float4* xp = (float4*)(X + ((size_t)(b * S_ + qg)) * D_ + h * HD_ + d0);
    float4 xv = *xp;
    xv.x += o[0] * inv; xv.y += o[1] * inv;
    xv.z += o[2] * inv; xv.w += o[3] * inv;
    *xp = xv;
}

// ---------------------------------------------------------------------------
// GEMM1: H[M,1024] = GELU(A[M,256] @ W[256,1024] + b1)   (M=16384)
// 64x64 tile, 256 threads, 4x4 microtile, BK=16. As transposed [k][m].
// ---------------------------------------------------------------------------
__global__ __launch_bounds__(256) void gemm1_kernel(
    const float* __restrict__ A, const float* __restrict__ W,
    const float* __restrict__ bias, float* __restrict__ C)
{
    __shared__ float As[16][72];
    __shared__ float Bs[16][68];
    int tid = threadIdx.x;
    int tx = tid & 15, ty = tid >> 4;
    int row0 = blockIdx.y * 64, col0 = blockIdx.x * 64;
    int lm = tid >> 2, lk = (tid & 3) * 4;     // A load: row lm, k lk
    int lbk = tid >> 4, lbn = (tid & 15) * 4;  // W load: k lbk, n lbn
    float acc[4][4] = {};
    for (int k0 = 0; k0 < 256; k0 += 16) {
        float4 av = *(const float4*)(A + (size_t)(row0 + lm) * 256 + k0 + lk);
        float4 bv = *(const float4*)(W + (size_t)(k0 + lbk) * 1024 + col0 + lbn);
        As[lk + 0][lm] = av.x;
        As[lk + 1][lm] = av.y;
        As[lk + 2][lm] = av.z;
        As[lk + 3][lm] = av.w;
        *(float4*)(&Bs[lbk][lbn]) = bv;
        __syncthreads();
        #pragma unroll
        for (int k = 0; k < 16; k++) {
            float4 a4 = *(const float4*)(&As[k][ty * 4]);
            float4 b4 = *(const float4*)(&Bs[k][tx * 4]);
            acc[0][0] += a4.x * b4.x; acc[0][1] += a4.x * b4.y;
            acc[0][2] += a4.x * b4.z; acc[0][3] += a4.x * b4.w;
            acc[1][0] += a4.y * b4.x; acc[1][1] += a4.y * b4.y;
            acc[1][2] += a4.y * b4.z; acc[1][3] += a4.y * b4.w;
            acc[2][0] += a4.z * b4.x; acc[2][1] += a4.z * b4.y;
            acc[2][2] += a4.z * b4.z; acc[2][3] += a4.z * b4.w;
            acc[3][0] += a4.w * b4.x; acc[3][1] += a4.w * b4.y;
            acc[3][2] += a4.w * b4.z; acc[3][3] += a4.w * b4.w;
        }
        __syncthreads();
    }
    float4 bb = *(const float4*)(bias + col0 + tx * 4);
    #pragma unroll
    for (int i = 0; i < 4; i++) {
        int row = row0 + ty * 4 + i;
        float4 o;
        float v0 = acc[i][0] + bb.x, v1 = acc[i][1] + bb.y;
        float v2 = acc[i][2] + bb.z, v3 = acc[i][3] + bb.w;
        o.x = 0.5f * v0 * (1.0f + erff(v0 * 0.70710678118654752f));
        o.y = 0.5f * v1 * (1.0f + erff(v1 * 0.70710678118654752f));
        o.z = 0.5f * v2 * (1.0f + erff(v2 * 0.70710678118654752f));
        o.w = 0.5f * v3 * (1.0f + erff(v3 * 0.70710678118654752f));
        *(float4*)(C + (size_t)row * 1024 + col0 + tx * 4) = o;
    }
}

// ---------------------------------------------------------------------------
// GEMM2: X[M,256] += A[M,1024] @ W[1024,256] + b2   (M=16384)
// ---------------------------------------------------------------------------
__global__ __launch_bounds__(256) void gemm2_kernel(
    const float* __restrict__ A, const float* __restrict__ W,
    const float* __restrict__ bias, float* __restrict__ X)
{
    __shared__ float As[16][72];
    __shared__ float Bs[16][68];
    int tid = threadIdx.x;
    int tx = tid & 15, ty = tid >> 4;
    int row0 = blockIdx.y * 64, col0 = blockIdx.x * 64;
    int lm = tid >> 2, lk = (tid & 3) * 4;
    int lbk = tid >> 4, lbn = (tid & 15) * 4;
    float acc[4][4] = {};
    for (int k0 = 0; k0 < 1024; k0 += 16) {
        float4 av = *(const float4*)(A + (size_t)(row0 + lm) * 1024 + k0 + lk);
        float4 bv = *(const float4*)(W + (size_t)(k0 + lbk) * 256 + col0 + lbn);
        As[lk + 0][lm] = av.x;
        As[lk + 1][lm] = av.y;
        As[lk + 2][lm] = av.z;
        As[lk + 3][lm] = av.w;
        *(float4*)(&Bs[lbk][lbn]) = bv;
        __syncthreads();
        #pragma unroll
        for (int k = 0; k < 16; k++) {
            float4 a4 = *(const float4*)(&As[k][ty * 4]);
            float4 b4 = *(const float4*)(&Bs[k][tx * 4]);
            acc[0][0] += a4.x * b4.x; acc[0][1] += a4.x * b4.y;
            acc[0][2] += a4.x * b4.z; acc[0][3] += a4.x * b4.w;
            acc[1][0] += a4.y * b4.x; acc[1][1] += a4.y * b4.y;
            acc[1][2] += a4.y * b4.z; acc[1][3] += a4.y * b4.w;
            acc[2][0] += a4.z * b4.x; acc[2][1] += a4.z * b4.y;
            acc[2][2] += a4.z * b4.z; acc[2][3] += a4.z * b4.w;
            acc[3][0] += a4.w * b4.x; acc[3][1] += a4.w * b4.y;
            acc[3][2] += a4.w * b4.z; acc[3][3] += a4.w * b4.w;
        }
        __syncthreads();
    }
    float4 bb = *(const float4*)(bias + col0 + tx * 4);
    #pragma unroll
    for (int i = 0; i < 4; i++) {
        int row = row0 + ty * 4 + i;
        float4* xp = (float4*)(X + (size_t)row * 256 + col0 + tx * 4);
        float4 xv = *xp;
        xv.x += acc[i][0] + bb.x;
        xv.y += acc[i][1] + bb.y;
        xv.z += acc[i][2] + bb.z;
        xv.w += acc[i][3] + bb.w;
        *xp = xv;
    }
}

// ---------------------------------------------------------------------------
extern "C" void kernel_launch(void* const* d_in, const int* in_sizes, int n_in,
                              void* d_out, int out_size, void* d_ws, size_t ws_size,
                              hipStream_t stream)
{
    const int*   tokens  = (const int*)d_in[0];
    const int*   pos_ids = (const int*)d_in[1];
    const float* emb     = (const float*)d_in[2];
    const float* iw      = (const float*)d_in[3];
    const float* pw      = (const float*)d_in[4];
    const float* ln1w    = (const float*)d_in[5];
    const float* ln1b    = (const float*)d_in[6];
    const float* ln2w    = (const float*)d_in[7];
    const float* ln2b    = (const float*)d_in[8];
    const float* w1      = (const float*)d_in[9];
    const float* b1      = (const float*)d_in[10];
    const float* w2      = (const float*)d_in[11];
    const float* b2      = (const float*)d_in[12];
    const float* lnfw    = (const float*)d_in[13];
    const float* lnfb    = (const float*)d_in[14];

    float* x  = (float*)d_out;                                   // [B,S,D] residual stream
    float* xn = (float*)d_ws;                                    // [B,S,D] LN output
    float* hb = (float*)((char*)d_ws + (size_t)B_ * S_ * D_ * 4); // [B,S,1024] MLP hidden

    embed_kernel<<<B_ * S_, 256, 0, stream>>>(tokens, pos_ids, emb, iw, pw, x);

    for (int l = 0; l < L_; l++) {
        ln_kernel<<<(B_ * S_) / 4, 256, 0, stream>>>(x, ln1w + l * D_, ln1b + l * D_, xn);
        attn_kernel<<<dim3(S_ / 32, B_ * H_), 256, 0, stream>>>(xn, x);
        ln_kernel<<<(B_ * S_) / 4, 256, 0, stream>>>(x, ln2w + l * D_, ln2b + l * D_, xn);
        gemm1_kernel<<<dim3(H2_ / 64, (B_ * S_) / 64), 256, 0, stream>>>(
            xn, w1 + (size_t)l * D_ * H2_, b1 + (size_t)l * H2_, hb);
        gemm2_kernel<<<dim3(D_ / 64, (B_ * S_) / 64), 256, 0, stream>>>(
            hb, w2 + (size_t)l * H2_ * D_, b2 + (size_t)l * D_, x);
    }
    ln_kernel<<<(B_ * S_) / 4, 256, 0, stream>>>(x, lnfw, lnfb, x);
}

// Round 2
// 1661.470 us; speedup vs baseline: 2.7147x; 2.7147x over previous
//
#include <hip/hip_runtime.h>
#include <hip/hip_bf16.h>
#include <math.h>

#define B_   16
#define S_   1024
#define D_   256
#define H_   8
#define HD_  32
#define L_   6
#define H2_  1024
#define LN_EPS 1e-5f
#define LOG2E_ 1.4426950408889634f
#define SCALE_ 0.17677669529663687f  // 1/sqrt(32)

typedef __attribute__((ext_vector_type(8))) short frag;    // 8 bf16 (4 VGPRs)
typedef __attribute__((ext_vector_type(4))) float f32x4;

#define MFMA(a, b, c) __builtin_amdgcn_mfma_f32_16x16x32_bf16((a), (b), (c), 0, 0, 0)

__device__ inline ushort bf16b(float f) {
    uint u = __builtin_bit_cast(uint, f);
    u += 0x7fff + ((u >> 16) & 1);       // RNE
    return (ushort)(u >> 16);
}

// ---------------------------------------------------------------------------
// f32 -> bf16 bulk convert (weights). n4 = elems/4.
// ---------------------------------------------------------------------------
__global__ __launch_bounds__(256) void cvt_kernel(
    const float* __restrict__ in, ushort* __restrict__ out, int n4)
{
    int i = blockIdx.x * 256 + threadIdx.x;
    if (i < n4) {
        float4 v = ((const float4*)in)[i];
        ushort4 o = { bf16b(v.x), bf16b(v.y), bf16b(v.z), bf16b(v.w) };
        ((ushort4*)out)[i] = o;
    }
}

// ---------------------------------------------------------------------------
// Embedding (f32 out)
// ---------------------------------------------------------------------------
__global__ __launch_bounds__(256) void embed_kernel(
    const int* __restrict__ tokens, const int* __restrict__ pos_ids,
    const float* __restrict__ emb, const float* __restrict__ iwp,
    const float* __restrict__ pwp, float* __restrict__ X)
{
    int bs = blockIdx.x;
    int s = bs & (S_ - 1);
    int d = threadIdx.x;
    int tok = tokens[bs];
    float p = (float)pos_ids[s];
    int j = (d < 128) ? d : (d - 128);
    float invf = exp2f(-(float)j * (13.287712379549449f / 128.0f));
    float ang = p * invf;
    float pe = (d < 128) ? sinf(ang) : cosf(ang);
    X[(size_t)bs * D_ + d] = iwp[0] * emb[tok * D_ + d] + pwp[0] * pe;
}

// ---------------------------------------------------------------------------
// LayerNorm: wave per row. MODE 0: f32 out row-major. MODE 1: bf16 head-packed
// [B][H][S][32]. MODE 2: bf16 row-major [M][256].
// ---------------------------------------------------------------------------
template<int MODE>
__global__ __launch_bounds__(256) void ln_kernel(
    const float* __restrict__ X, const float* __restrict__ w,
    const float* __restrict__ b, void* __restrict__ outp)
{
    int row = blockIdx.x * 4 + (threadIdx.x >> 6);
    int lane = threadIdx.x & 63;
    const float4 v = *(const float4*)(X + (size_t)row * D_ + lane * 4);
    float s = v.x + v.y + v.z + v.w;
    #pragma unroll
    for (int m = 1; m < 64; m <<= 1) s += __shfl_xor(s, m, 64);
    float mu = s * (1.0f / 256.0f);
    float dx = v.x - mu, dy = v.y - mu, dz = v.z - mu, dw = v.w - mu;
    float vs = dx * dx + dy * dy + dz * dz + dw * dw;
    #pragma unroll
    for (int m = 1; m < 64; m <<= 1) vs += __shfl_xor(vs, m, 64);
    float inv = rsqrtf(vs * (1.0f / 256.0f) + LN_EPS);
    float4 wv = *(const float4*)(w + lane * 4);
    float4 bv = *(const float4*)(b + lane * 4);
    float o0 = dx * inv * wv.x + bv.x;
    float o1 = dy * inv * wv.y + bv.y;
    float o2 = dz * inv * wv.z + bv.z;
    float o3 = dw * inv * wv.w + bv.w;
    if constexpr (MODE == 0) {
        float4 o = { o0, o1, o2, o3 };
        *(float4*)((float*)outp + (size_t)row * D_ + lane * 4) = o;
    } else if constexpr (MODE == 1) {
        int bb = row >> 10, ss = row & 1023;
        int h = lane >> 3, dd = (lane & 7) * 4;
        ushort4 o = { bf16b(o0), bf16b(o1), bf16b(o2), bf16b(o3) };
        *(ushort4*)((ushort*)outp + (((size_t)(bb * H_ + h) * S_ + ss) * HD_ + dd)) = o;
    } else {
        ushort4 o = { bf16b(o0), bf16b(o1), bf16b(o2), bf16b(o3) };
        *(ushort4*)((ushort*)outp + (size_t)row * D_ + lane * 4) = o;
    }
}

// ---------------------------------------------------------------------------
// Flash attention, bf16 MFMA. Block: 256 thr = 4 waves, 64 q-rows.
// Wave w: 16 q-rows (16x16x32 mfma tiles). Per kv-tile of 32:
//   QK^T: A=Q frag (global), B=K frag (global);  scores D: row=(l>>4)*4+r, col=l&15
//   softmax in-register per row-group; P packed to LDS (slot-interleaved),
//   PV: A=P frag, B=V frag from transposed Vt LDS (staged once per block).
// Adds O/l into X (residual). grid (S/64, B*H).
// Slot order for PV contraction: slot(t) = 2*(t&15) + ((t>>4)&1)  (t local in tile)
// ---------------------------------------------------------------------------
__global__ __launch_bounds__(256) void attn_kernel(
    const ushort* __restrict__ XNB, float* __restrict__ X)
{
    __shared__ ushort Vt[32 * 1032];      // [d][slot-col], stride 1032 (2064B, 16B-aligned)
    __shared__ ushort Pl[4][16][40];      // per-wave P, stride 40 (80B)

    const int bh = blockIdx.y;
    const int b = bh >> 3, h = bh & 7;
    const ushort* __restrict__ base = XNB + (size_t)bh * (S_ * HD_);
    const int tid = threadIdx.x;

    // ---- stage V transposed (once) ----
    #pragma unroll
    for (int i = 0; i < 16; ++i) {
        int cid = i * 256 + tid;          // 4096 chunks of 8 bf16
        int t = cid >> 2, c = cid & 3;
        uint4 u = *(const uint4*)(base + t * HD_ + c * 8);
        int col = ((t >> 5) << 5) + 2 * (t & 15) + ((t >> 4) & 1);
        int d0 = c * 8;
        Vt[(d0 + 0) * 1032 + col] = (ushort)(u.x & 0xffff);
        Vt[(d0 + 1) * 1032 + col] = (ushort)(u.x >> 16);
        Vt[(d0 + 2) * 1032 + col] = (ushort)(u.y & 0xffff);
        Vt[(d0 + 3) * 1032 + col] = (ushort)(u.y >> 16);
        Vt[(d0 + 4) * 1032 + col] = (ushort)(u.z & 0xffff);
        Vt[(d0 + 5) * 1032 + col] = (ushort)(u.z >> 16);
        Vt[(d0 + 6) * 1032 + col] = (ushort)(u.w & 0xffff);
        Vt[(d0 + 7) * 1032 + col] = (ushort)(u.w >> 16);
    }
    __syncthreads();

    const int w = tid >> 6, l = tid & 63;
    const int g = l >> 4, ll = l & 15;
    const int q0 = blockIdx.x * 64 + w * 16;

    frag qf = *(const frag*)(base + (size_t)(q0 + ll) * HD_ + g * 8);

    int qr[4], xq[4], yq[4];
    #pragma unroll
    for (int r = 0; r < 4; ++r) {
        qr[r] = q0 + g * 4 + r;
        xq[r] = qr[r] >> 5;
        yq[r] = qr[r] & 31;
    }
    const float C1 = SCALE_ * LOG2E_;
    const float slr = -exp2f(-(0.5f + (float)h)) * LOG2E_;
    const float sll = -exp2f(-(1.0f + (float)h)) * LOG2E_;

    float mreg[4] = { -3e38f, -3e38f, -3e38f, -3e38f };
    float lsum[4] = { 0.f, 0.f, 0.f, 0.f };
    f32x4 o0 = { 0.f, 0.f, 0.f, 0.f };
    f32x4 o1 = { 0.f, 0.f, 0.f, 0.f };
    const f32x4 zc = { 0.f, 0.f, 0.f, 0.f };

    frag kf0 = *(const frag*)(base + (size_t)(0 + ll) * HD_ + g * 8);
    frag kf1 = *(const frag*)(base + (size_t)(16 + ll) * HD_ + g * 8);

    for (int it = 0; it < 32; ++it) {
        int tb = it * 32;
        int nt = (it < 31) ? tb + 32 : tb;   // prefetch next K (redundant on last)
        frag nk0 = *(const frag*)(base + (size_t)(nt + ll) * HD_ + g * 8);
        frag nk1 = *(const frag*)(base + (size_t)(nt + 16 + ll) * HD_ + g * 8);

        f32x4 s0 = MFMA(qf, kf0, zc);
        f32x4 s1 = MFMA(qf, kf1, zc);

        int t0g = tb + ll, t1g = tb + 16 + ll;
        int xt0 = t0g >> 5, yt0 = t0g & 31;
        int xt1 = t1g >> 5, yt1 = t1g & 31;

        #pragma unroll
        for (int r = 0; r < 4; ++r) {
            int d0 = abs(xq[r] - xt0) + abs(yq[r] - yt0);
            int d1 = abs(xq[r] - xt1) + abs(yq[r] - yt1);
            float v0 = s0[r] * C1 + (t0g > qr[r] ? slr : sll) * (float)d0;
            float v1 = s1[r] * C1 + (t1g > qr[r] ? slr : sll) * (float)d1;
            float tm = fmaxf(v0, v1);
            tm = fmaxf(tm, __shfl_xor(tm, 1, 16));
            tm = fmaxf(tm, __shfl_xor(tm, 2, 16));
            tm = fmaxf(tm, __shfl_xor(tm, 4, 16));
            tm = fmaxf(tm, __shfl_xor(tm, 8, 16));
            float mn = fmaxf(mreg[r], tm);
            float al = exp2f(mreg[r] - mn);
            mreg[r] = mn;
            float e0 = exp2f(v0 - mn);
            float e1 = exp2f(v1 - mn);
            float ps = e0 + e1;
            ps += __shfl_xor(ps, 1, 16);
            ps += __shfl_xor(ps, 2, 16);
            ps += __shfl_xor(ps, 4, 16);
            ps += __shfl_xor(ps, 8, 16);
            lsum[r] = lsum[r] * al + ps;
            o0[r] *= al; o1[r] *= al;
            uint pw = (uint)bf16b(e0) | ((uint)bf16b(e1) << 16);  // slots 2ll, 2ll+1
            *(uint*)&Pl[w][g * 4 + r][2 * ll] = pw;
        }
        // wave-internal LDS round-trip (DS ops in-order per wave; no barrier)
        frag pf  = *(const frag*)&Pl[w][ll][g * 8];
        frag vf0 = *(const frag*)&Vt[(ll)      * 1032 + tb + g * 8];
        frag vf1 = *(const frag*)&Vt[(16 + ll) * 1032 + tb + g * 8];
        o0 = MFMA(pf, vf0, o0);
        o1 = MFMA(pf, vf1, o1);
        kf0 = nk0; kf1 = nk1;
    }

    #pragma unroll
    for (int r = 0; r < 4; ++r) {
        float inv = 1.0f / lsum[r];
        float* xp = X + ((size_t)(b * S_ + qr[r])) * D_ + h * HD_;
        xp[ll]      += o0[r] * inv;
        xp[16 + ll] += o1[r] * inv;
    }
}

// ---------------------------------------------------------------------------
// GEMM1: H[16384,1024] = GELU(A[16384,256]_bf16 @ W[256,1024]_bf16 + b1), bf16 out
// 128x128 tile, 4 waves, each 64x64 (4x4 frags of 16x16), BK=32.
// ---------------------------------------------------------------------------
__global__ __launch_bounds__(256) void gemm1_kernel(
    const ushort* __restrict__ A, const ushort* __restrict__ Bw,
    const float* __restrict__ bias, ushort* __restrict__ Hout)
{
    __shared__ ushort As[128 * 40];
    __shared__ ushort Bt[128 * 40];
    const int tid = threadIdx.x;
    const int w = tid >> 6, l = tid & 63, g = l >> 4, ll = l & 15;
    const int wm = w >> 1, wn = w & 1;
    const int row0 = blockIdx.y * 128, col0 = blockIdx.x * 128;
    f32x4 acc[4][4] = {};

    for (int k0 = 0; k0 < 256; k0 += 32) {
        #pragma unroll
        for (int i = 0; i < 2; ++i) {
            int cid = i * 256 + tid;
            int m = cid >> 2, kc = cid & 3;
            *(uint4*)&As[m * 40 + kc * 8] =
                *(const uint4*)(A + (size_t)(row0 + m) * 256 + k0 + kc * 8);
        }
        #pragma unroll
        for (int i = 0; i < 2; ++i) {
            int cid = i * 256 + tid;
            int k = cid >> 4, nc = cid & 15;
            uint4 u = *(const uint4*)(Bw + (size_t)(k0 + k) * 1024 + col0 + nc * 8);
            int nb = (nc * 8) * 40 + k;
            Bt[nb + 0 * 40] = (ushort)(u.x & 0xffff);
            Bt[nb + 1 * 40] = (ushort)(u.x >> 16);
            Bt[nb + 2 * 40] = (ushort)(u.y & 0xffff);
            Bt[nb + 3 * 40] = (ushort)(u.y >> 16);
            Bt[nb + 4 * 40] = (ushort)(u.z & 0xffff);
            Bt[nb + 5 * 40] = (ushort)(u.z >> 16);
            Bt[nb + 6 * 40] = (ushort)(u.w & 0xffff);
            Bt[nb + 7 * 40] = (ushort)(u.w >> 16);
        }
        __syncthreads();
        frag af[4], bfr[4];
        #pragma unroll
        for (int mb = 0; mb < 4; ++mb)
            af[mb] = *(const frag*)&As[(wm * 64 + mb * 16 + ll) * 40 + g * 8];
        #pragma unroll
        for (int nb = 0; nb < 4; ++nb)
            bfr[nb] = *(const frag*)&Bt[(wn * 64 + nb * 16 + ll) * 40 + g * 8];
        #pragma unroll
        for (int mb = 0; mb < 4; ++mb)
            #pragma unroll
            for (int nb = 0; nb < 4; ++nb)
                acc[mb][nb] = MFMA(af[mb], bfr[nb], acc[mb][nb]);
        __syncthreads();
    }

    #pragma unroll
    for (int nb = 0; nb < 4; ++nb) {
        int col = col0 + wn * 64 + nb * 16 + ll;
        float bv = bias[col];
        #pragma unroll
        for (int mb = 0; mb < 4; ++mb) {
            #pragma unroll
            for (int r = 0; r < 4; ++r) {
                int row = row0 + wm * 64 + mb * 16 + g * 4 + r;
                float v = acc[mb][nb][r] + bv;
                // gelu(v) = v * (1 - 1/(exp(2u)+1)), u = 0.79788456(v + 0.044715 v^3)
                float u2 = 1.5957691216f * v + 0.0713548162f * (v * v * v);
                float e = exp2f(u2 * LOG2E_);
                float rr = __builtin_amdgcn_rcpf(e + 1.0f);
                float gl = v - v * rr;
                Hout[(size_t)row * 1024 + col] = bf16b(gl);
            }
        }
    }
}

// ---------------------------------------------------------------------------
// GEMM2: X[16384,256] += A[16384,1024]_bf16 @ W[1024,256]_bf16 + b2
// ---------------------------------------------------------------------------
__global__ __launch_bounds__(256) void gemm2_kernel(
    const ushort* __restrict__ A, const ushort* __restrict__ Bw,
    const float* __restrict__ bias, float* __restrict__ X)
{
    __shared__ ushort As[128 * 40];
    __shared__ ushort Bt[128 * 40];
    const int tid = threadIdx.x;
    const int w = tid >> 6, l = tid & 63, g = l >> 4, ll = l & 15;
    const int wm = w >> 1, wn = w & 1;
    const int row0 = blockIdx.y * 128, col0 = blockIdx.x * 128;
    f32x4 acc[4][4] = {};

    for (int k0 = 0; k0 < 1024; k0 += 32) {
        #pragma unroll
        for (int i = 0; i < 2; ++i) {
            int cid = i * 256 + tid;
            int m = cid >> 2, kc = cid & 3;
            *(uint4*)&As[m * 40 + kc * 8] =
                *(const uint4*)(A + (size_t)(row0 + m) * 1024 + k0 + kc * 8);
        }
        #pragma unroll
        for (int i = 0; i < 2; ++i) {
            int cid = i * 256 + tid;
            int k = cid >> 4, nc = cid & 15;
            uint4 u = *(const uint4*)(Bw + (size_t)(k0 + k) * 256 + col0 + nc * 8);
            int nb = (nc * 8) * 40 + k;
            Bt[nb + 0 * 40] = (ushort)(u.x & 0xffff);
            Bt[nb + 1 * 40] = (ushort)(u.x >> 16);
            Bt[nb + 2 * 40] = (ushort)(u.y & 0xffff);
            Bt[nb + 3 * 40] = (ushort)(u.y >> 16);
            Bt[nb + 4 * 40] = (ushort)(u.z & 0xffff);
            Bt[nb + 5 * 40] = (ushort)(u.z >> 16);
            Bt[nb + 6 * 40] = (ushort)(u.w & 0xffff);
            Bt[nb + 7 * 40] = (ushort)(u.w >> 16);
        }
        __syncthreads();
        frag af[4], bfr[4];
        #pragma unroll
        for (int mb = 0; mb < 4; ++mb)
            af[mb] = *(const frag*)&As[(wm * 64 + mb * 16 + ll) * 40 + g * 8];
        #pragma unroll
        for (int nb = 0; nb < 4; ++nb)
            bfr[nb] = *(const frag*)&Bt[(wn * 64 + nb * 16 + ll) * 40 + g * 8];
        #pragma unroll
        for (int mb = 0; mb < 4; ++mb)
            #pragma unroll
            for (int nb = 0; nb < 4; ++nb)
                acc[mb][nb] = MFMA(af[mb], bfr[nb], acc[mb][nb]);
        __syncthreads();
    }

    #pragma unroll
    for (int nb = 0; nb < 4; ++nb) {
        int col = col0 + wn * 64 + nb * 16 + ll;
        float bv = bias[col];
        #pragma unroll
        for (int mb = 0; mb < 4; ++mb) {
            #pragma unroll
            for (int r = 0; r < 4; ++r) {
                int row = row0 + wm * 64 + mb * 16 + g * 4 + r;
                float* xp = X + (size_t)row * 256 + col;
                *xp += acc[mb][nb][r] + bv;
            }
        }
    }
}

// ---------------------------------------------------------------------------
extern "C" void kernel_launch(void* const* d_in, const int* in_sizes, int n_in,
                              void* d_out, int out_size, void* d_ws, size_t ws_size,
                              hipStream_t stream)
{
    const int*   tokens  = (const int*)d_in[0];
    const int*   pos_ids = (const int*)d_in[1];
    const float* emb     = (const float*)d_in[2];
    const float* iw      = (const float*)d_in[3];
    const float* pw      = (const float*)d_in[4];
    const float* ln1w    = (const float*)d_in[5];
    const float* ln1b    = (const float*)d_in[6];
    const float* ln2w    = (const float*)d_in[7];
    const float* ln2b    = (const float*)d_in[8];
    const float* w1      = (const float*)d_in[9];
    const float* b1      = (const float*)d_in[10];
    const float* w2      = (const float*)d_in[11];
    const float* b2      = (const float*)d_in[12];
    const float* lnfw    = (const float*)d_in[13];
    const float* lnfb    = (const float*)d_in[14];

    float* x = (float*)d_out;                 // [B,S,D] f32 residual stream
    char* ws = (char*)d_ws;
    ushort* xnb_attn = (ushort*)ws;                          // 8,388,608 B
    ushort* xnb_mlp  = (ushort*)(ws + 8388608);              // 8,388,608 B
    ushort* hbuf     = (ushort*)(ws + 16777216);             // 33,554,432 B
    ushort* w1b      = (ushort*)(ws + 50331648);             // 3,145,728 B
    ushort* w2b      = (ushort*)(ws + 53477376);             // 3,145,728 B

    const int wn4 = L_ * D_ * H2_ / 4;   // 393216
    cvt_kernel<<<(wn4 + 255) / 256, 256, 0, stream>>>(w1, w1b, wn4);
    cvt_kernel<<<(wn4 + 255) / 256, 256, 0, stream>>>(w2, w2b, wn4);

    embed_kernel<<<B_ * S_, 256, 0, stream>>>(tokens, pos_ids, emb, iw, pw, x);

    for (int l = 0; l < L_; l++) {
        ln_kernel<1><<<(B_ * S_) / 4, 256, 0, stream>>>(x, ln1w + l * D_, ln1b + l * D_, xnb_attn);
        attn_kernel<<<dim3(S_ / 64, B_ * H_), 256, 0, stream>>>(xnb_attn, x);
        ln_kernel<2><<<(B_ * S_) / 4, 256, 0, stream>>>(x, ln2w + l * D_, ln2b + l * D_, xnb_mlp);
        gemm1_kernel<<<dim3(H2_ / 128, (B_ * S_) / 128), 256, 0, stream>>>(
            xnb_mlp, w1b + (size_t)l * D_ * H2_, b1 + (size_t)l * H2_, hbuf);
        gemm2_kernel<<<dim3(D_ / 128, (B_ * S_) / 128), 256, 0, stream>>>(
            hbuf, w2b + (size_t)l * H2_ * D_, b2 + (size_t)l * D_, x);
    }
    ln_kernel<0><<<(B_ * S_) / 4, 256, 0, stream>>>(x, lnfw, lnfb, x);
}

// Round 3
// 1033.676 us; speedup vs baseline: 4.3634x; 1.6073x over previous
//
#include <hip/hip_runtime.h>
#include <hip/hip_bf16.h>
#include <math.h>

#define B_   16
#define S_   1024
#define D_   256
#define H_   8
#define HD_  32
#define L_   6
#define H2_  1024
#define LN_EPS 1e-5f
#define LOG2E_ 1.4426950408889634f
#define SCALE_ 0.17677669529663687f  // 1/sqrt(32)
#define THR_ 12.0f                   // defer-max threshold (log2 domain): P <= 2^12

typedef __attribute__((ext_vector_type(8))) short frag;    // 8 bf16 (4 VGPRs)
typedef __attribute__((ext_vector_type(4))) float f32x4;

#define MFMA(a, b, c) __builtin_amdgcn_mfma_f32_16x16x32_bf16((a), (b), (c), 0, 0, 0)

__device__ inline ushort bf16b(float f) {
    uint u = __builtin_bit_cast(uint, f);
    u += 0x7fff + ((u >> 16) & 1);       // RNE
    return (ushort)(u >> 16);
}
__device__ inline uint cvt_pk_bf16(float lo, float hi) {
    uint r;
    asm("v_cvt_pk_bf16_f32 %0, %1, %2" : "=v"(r) : "v"(lo), "v"(hi));
    return r;
}
__device__ inline uint sad_u8(uint a, uint b) {   // sum of |byte diffs|
    uint d;
    asm("v_sad_u8 %0, %1, %2, 0" : "=v"(d) : "v"(a), "v"(b));
    return d;
}

// ---------------------------------------------------------------------------
// Weight transpose + f32->bf16: in [K][N] f32 -> out [N][K] bf16 (per layer z)
// ---------------------------------------------------------------------------
__global__ __launch_bounds__(256) void wtr_kernel(
    const float* __restrict__ in, ushort* __restrict__ out, int K, int N)
{
    __shared__ ushort Ts[32][36];
    in  += (size_t)blockIdx.z * K * N;
    out += (size_t)blockIdx.z * K * N;
    int n0 = blockIdx.x * 32, k0 = blockIdx.y * 32;
    int r = threadIdx.x >> 3, c4 = (threadIdx.x & 7) * 4;
    float4 f = *(const float4*)(in + (size_t)(k0 + r) * N + n0 + c4);
    Ts[r][c4 + 0] = bf16b(f.x);
    Ts[r][c4 + 1] = bf16b(f.y);
    Ts[r][c4 + 2] = bf16b(f.z);
    Ts[r][c4 + 3] = bf16b(f.w);
    __syncthreads();
    ushort4 o = { Ts[c4 + 0][r], Ts[c4 + 1][r], Ts[c4 + 2][r], Ts[c4 + 3][r] };
    *(ushort4*)(out + (size_t)(n0 + r) * K + k0 + c4) = o;
}

// ---------------------------------------------------------------------------
// Embedding (f32 out)
// ---------------------------------------------------------------------------
__global__ __launch_bounds__(256) void embed_kernel(
    const int* __restrict__ tokens, const int* __restrict__ pos_ids,
    const float* __restrict__ emb, const float* __restrict__ iwp,
    const float* __restrict__ pwp, float* __restrict__ X)
{
    int bs = blockIdx.x;
    int s = bs & (S_ - 1);
    int d = threadIdx.x;
    int tok = tokens[bs];
    float p = (float)pos_ids[s];
    int j = (d < 128) ? d : (d - 128);
    float invf = exp2f(-(float)j * (13.287712379549449f / 128.0f));
    float ang = p * invf;
    float pe = (d < 128) ? sinf(ang) : cosf(ang);
    X[(size_t)bs * D_ + d] = iwp[0] * emb[tok * D_ + d] + pwp[0] * pe;
}

// ---------------------------------------------------------------------------
// LayerNorm: wave per row. MODE 0: f32 row-major. MODE 1: bf16 head-packed
// [B][H][S][32]. MODE 2: bf16 row-major [M][256].
// ---------------------------------------------------------------------------
template<int MODE>
__global__ __launch_bounds__(256) void ln_kernel(
    const float* __restrict__ X, const float* __restrict__ w,
    const float* __restrict__ b, void* __restrict__ outp)
{
    int row = blockIdx.x * 4 + (threadIdx.x >> 6);
    int lane = threadIdx.x & 63;
    const float4 v = *(const float4*)(X + (size_t)row * D_ + lane * 4);
    float s = v.x + v.y + v.z + v.w;
    #pragma unroll
    for (int m = 1; m < 64; m <<= 1) s += __shfl_xor(s, m, 64);
    float mu = s * (1.0f / 256.0f);
    float dx = v.x - mu, dy = v.y - mu, dz = v.z - mu, dw = v.w - mu;
    float vs = dx * dx + dy * dy + dz * dz + dw * dw;
    #pragma unroll
    for (int m = 1; m < 64; m <<= 1) vs += __shfl_xor(vs, m, 64);
    float inv = rsqrtf(vs * (1.0f / 256.0f) + LN_EPS);
    float4 wv = *(const float4*)(w + lane * 4);
    float4 bv = *(const float4*)(b + lane * 4);
    float o0 = dx * inv * wv.x + bv.x;
    float o1 = dy * inv * wv.y + bv.y;
    float o2 = dz * inv * wv.z + bv.z;
    float o3 = dw * inv * wv.w + bv.w;
    if constexpr (MODE == 0) {
        float4 o = { o0, o1, o2, o3 };
        *(float4*)((float*)outp + (size_t)row * D_ + lane * 4) = o;
    } else if constexpr (MODE == 1) {
        int bb = row >> 10, ss = row & 1023;
        int h = lane >> 3, dd = (lane & 7) * 4;
        ushort4 o = { bf16b(o0), bf16b(o1), bf16b(o2), bf16b(o3) };
        *(ushort4*)((ushort*)outp + (((size_t)(bb * H_ + h) * S_ + ss) * HD_ + dd)) = o;
    } else {
        ushort4 o = { bf16b(o0), bf16b(o1), bf16b(o2), bf16b(o3) };
        *(ushort4*)((ushort*)outp + (size_t)row * D_ + lane * 4) = o;
    }
}

// ---------------------------------------------------------------------------
// V transpose: XNB [bh][s][32] -> VTI [bh][d][s'] where within each 32-block
// of s, col(s) = 2*(s&15) + ((s>>4)&1)  (slot interleave matching P packing).
// grid (S/128, B*H), 256 threads.
// ---------------------------------------------------------------------------
__global__ __launch_bounds__(256) void vtr_kernel(
    const ushort* __restrict__ XNB, ushort* __restrict__ VTI)
{
    __shared__ ushort Ts[32][136];
    const int bh = blockIdx.y;
    const int sblk = blockIdx.x * 128;
    const ushort* __restrict__ base = XNB + (size_t)bh * (S_ * HD_);
    #pragma unroll
    for (int i = 0; i < 2; ++i) {
        int cid = i * 256 + threadIdx.x;
        int s = cid >> 2, c = cid & 3;
        uint4 u = *(const uint4*)(base + (size_t)(sblk + s) * HD_ + c * 8);
        int col = ((s >> 5) << 5) + 2 * (s & 15) + ((s >> 4) & 1);
        int d0 = c * 8;
        Ts[d0 + 0][col] = (ushort)(u.x & 0xffff);
        Ts[d0 + 1][col] = (ushort)(u.x >> 16);
        Ts[d0 + 2][col] = (ushort)(u.y & 0xffff);
        Ts[d0 + 3][col] = (ushort)(u.y >> 16);
        Ts[d0 + 4][col] = (ushort)(u.z & 0xffff);
        Ts[d0 + 5][col] = (ushort)(u.z >> 16);
        Ts[d0 + 6][col] = (ushort)(u.w & 0xffff);
        Ts[d0 + 7][col] = (ushort)(u.w >> 16);
    }
    __syncthreads();
    #pragma unroll
    for (int i = 0; i < 2; ++i) {
        int cid = i * 256 + threadIdx.x;
        int d = cid >> 4, ch = cid & 15;
        uint4 o = *(const uint4*)&Ts[d][ch * 8];
        *(uint4*)(VTI + ((size_t)bh * HD_ + d) * S_ + sblk + ch * 8) = o;
    }
}

// ---------------------------------------------------------------------------
// Flash attention, bf16 MFMA, 64-key rounds. 4 waves x 16 q-rows, no barriers.
// Softmax: defer-max (THR), sum via ones-MFMA, bias via v_sad_u8.
// grid (S/64, B*H).
// ---------------------------------------------------------------------------
__global__ __launch_bounds__(256) void attn_kernel(
    const ushort* __restrict__ XNB, const ushort* __restrict__ VTI,
    float* __restrict__ X)
{
    __shared__ ushort Pl[4][16][72];   // per-wave P: 16 rows x 64 slots (+pad)

    const int bh = blockIdx.y;
    const int b = bh >> 3, h = bh & 7;
    const ushort* __restrict__ base = XNB + (size_t)bh * (S_ * HD_);
    const ushort* __restrict__ vbase = VTI + (size_t)bh * (HD_ * S_);
    const int tid = threadIdx.x;
    const int w = tid >> 6, l = tid & 63, g = l >> 4, ll = l & 15;
    const int q0 = blockIdx.x * 64 + w * 16;

    frag qf = *(const frag*)(base + (size_t)(q0 + ll) * HD_ + g * 8);

    int qr[4]; uint qp[4];
    #pragma unroll
    for (int r = 0; r < 4; ++r) {
        qr[r] = q0 + g * 4 + r;
        qp[r] = (uint)(qr[r] >> 5) | ((uint)(qr[r] & 31) << 8);
    }
    const float C1 = SCALE_ * LOG2E_;
    const float slr = -exp2f(-(0.5f + (float)h)) * LOG2E_;
    const float sll = -exp2f(-(1.0f + (float)h)) * LOG2E_;

    float mreg[4] = { -3e38f, -3e38f, -3e38f, -3e38f };
    f32x4 o0 = { 0.f, 0.f, 0.f, 0.f };
    f32x4 o1 = { 0.f, 0.f, 0.f, 0.f };
    f32x4 os = { 0.f, 0.f, 0.f, 0.f };
    const f32x4 zc = { 0.f, 0.f, 0.f, 0.f };
    const short one_s = (short)0x3F80;
    const frag ones = { one_s, one_s, one_s, one_s, one_s, one_s, one_s, one_s };

    int tb_l[4]; uint kp[4];
    #pragma unroll
    for (int j = 0; j < 4; ++j) {
        tb_l[j] = j * 16 + ll;
        kp[j] = (uint)(tb_l[j] >> 5) | ((uint)(tb_l[j] & 31) << 8);
    }
    frag kf0 = *(const frag*)(base + (size_t)(tb_l[0]) * HD_ + g * 8);
    frag kf1 = *(const frag*)(base + (size_t)(tb_l[1]) * HD_ + g * 8);
    frag kf2 = *(const frag*)(base + (size_t)(tb_l[2]) * HD_ + g * 8);
    frag kf3 = *(const frag*)(base + (size_t)(tb_l[3]) * HD_ + g * 8);

    for (int it = 0; it < 16; ++it) {
        const int tb = it * 64;
        const int nt = (it < 15) ? tb + 64 : tb;
        frag nk0 = *(const frag*)(base + (size_t)(nt + tb_l[0]) * HD_ + g * 8);
        frag nk1 = *(const frag*)(base + (size_t)(nt + tb_l[1]) * HD_ + g * 8);
        frag nk2 = *(const frag*)(base + (size_t)(nt + tb_l[2]) * HD_ + g * 8);
        frag nk3 = *(const frag*)(base + (size_t)(nt + tb_l[3]) * HD_ + g * 8);
        frag vf0 = *(const frag*)(vbase + (size_t)(ll)      * S_ + tb + g * 8);
        frag vf1 = *(const frag*)(vbase + (size_t)(16 + ll) * S_ + tb + g * 8);
        frag vf2 = *(const frag*)(vbase + (size_t)(ll)      * S_ + tb + 32 + g * 8);
        frag vf3 = *(const frag*)(vbase + (size_t)(16 + ll) * S_ + tb + 32 + g * 8);

        f32x4 s0 = MFMA(qf, kf0, zc);
        f32x4 s1 = MFMA(qf, kf1, zc);
        f32x4 s2 = MFMA(qf, kf2, zc);
        f32x4 s3 = MFMA(qf, kf3, zc);

        float vv[4][4]; float lm[4];
        #pragma unroll
        for (int r = 0; r < 4; ++r) {
            float sj0 = s0[r], sj1 = s1[r], sj2 = s2[r], sj3 = s3[r];
            float d0 = (float)sad_u8(qp[r], kp[0]);
            float d1 = (float)sad_u8(qp[r], kp[1]);
            float d2 = (float)sad_u8(qp[r], kp[2]);
            float d3 = (float)sad_u8(qp[r], kp[3]);
            float p0 = (tb + tb_l[0] > qr[r]) ? slr : sll;
            float p1 = (tb + tb_l[1] > qr[r]) ? slr : sll;
            float p2 = (tb + tb_l[2] > qr[r]) ? slr : sll;
            float p3 = (tb + tb_l[3] > qr[r]) ? slr : sll;
            vv[r][0] = sj0 * C1 + p0 * d0;
            vv[r][1] = sj1 * C1 + p1 * d1;
            vv[r][2] = sj2 * C1 + p2 * d2;
            vv[r][3] = sj3 * C1 + p3 * d3;
            lm[r] = fmaxf(fmaxf(vv[r][0], vv[r][1]), fmaxf(vv[r][2], vv[r][3]));
        }
        bool need = (lm[0] > mreg[0] + THR_) | (lm[1] > mreg[1] + THR_) |
                    (lm[2] > mreg[2] + THR_) | (lm[3] > mreg[3] + THR_);
        if (__any(need)) {
            #pragma unroll
            for (int r = 0; r < 4; ++r) {
                float tm = lm[r];
                tm = fmaxf(tm, __shfl_xor(tm, 1, 16));
                tm = fmaxf(tm, __shfl_xor(tm, 2, 16));
                tm = fmaxf(tm, __shfl_xor(tm, 4, 16));
                tm = fmaxf(tm, __shfl_xor(tm, 8, 16));
                float mn = fmaxf(mreg[r], tm);
                float al = exp2f(mreg[r] - mn);
                mreg[r] = mn;
                o0[r] *= al; o1[r] *= al; os[r] *= al;
            }
        }
        #pragma unroll
        for (int r = 0; r < 4; ++r) {
            float e0 = exp2f(vv[r][0] - mreg[r]);
            float e1 = exp2f(vv[r][1] - mreg[r]);
            float e2 = exp2f(vv[r][2] - mreg[r]);
            float e3 = exp2f(vv[r][3] - mreg[r]);
            *(uint*)&Pl[w][g * 4 + r][2 * ll]      = cvt_pk_bf16(e0, e1);
            *(uint*)&Pl[w][g * 4 + r][32 + 2 * ll] = cvt_pk_bf16(e2, e3);
        }
        frag pf0 = *(const frag*)&Pl[w][ll][g * 8];
        frag pf1 = *(const frag*)&Pl[w][ll][32 + g * 8];
        o0 = MFMA(pf0, vf0, o0);
        o1 = MFMA(pf0, vf1, o1);
        os = MFMA(pf0, ones, os);
        o0 = MFMA(pf1, vf2, o0);
        o1 = MFMA(pf1, vf3, o1);
        os = MFMA(pf1, ones, os);
        kf0 = nk0; kf1 = nk1; kf2 = nk2; kf3 = nk3;
        kp[0] += 2; kp[1] += 2; kp[2] += 2; kp[3] += 2;
    }

    #pragma unroll
    for (int r = 0; r < 4; ++r) {
        float inv = 1.0f / os[r];
        float* xp = X + ((size_t)(b * S_ + qr[r])) * D_ + h * HD_;
        xp[ll]      += o0[r] * inv;
        xp[16 + ll] += o1[r] * inv;
    }
}

// ---------------------------------------------------------------------------
// GEMM1: H[16384,1024] = GELU(A[16384,256]_bf16 @ W^T-stored[1024,256] + b1)
// 128x128 tile, 4 waves, 4x4 frags, BK=32. Both stagings straight b128.
// ---------------------------------------------------------------------------
__global__ __launch_bounds__(256) void gemm1_kernel(
    const ushort* __restrict__ A, const ushort* __restrict__ Bt,
    const float* __restrict__ bias, ushort* __restrict__ Hout)
{
    __shared__ ushort As[128 * 40];
    __shared__ ushort Bs[128 * 40];
    const int tid = threadIdx.x;
    const int w = tid >> 6, l = tid & 63, g = l >> 4, ll = l & 15;
    const int wm = w >> 1, wn = w & 1;
    const int row0 = blockIdx.y * 128, col0 = blockIdx.x * 128;
    f32x4 acc[4][4] = {};

    for (int k0 = 0; k0 < 256; k0 += 32) {
        #pragma unroll
        for (int i = 0; i < 2; ++i) {
            int cid = i * 256 + tid;
            int m = cid >> 2, c = cid & 3;
            *(uint4*)&As[m * 40 + c * 8] =
                *(const uint4*)(A + (size_t)(row0 + m) * 256 + k0 + c * 8);
            *(uint4*)&Bs[m * 40 + c * 8] =
                *(const uint4*)(Bt + (size_t)(col0 + m) * 256 + k0 + c * 8);
        }
        __syncthreads();
        frag af[4], bfr[4];
        #pragma unroll
        for (int mb = 0; mb < 4; ++mb)
            af[mb] = *(const frag*)&As[(wm * 64 + mb * 16 + ll) * 40 + g * 8];
        #pragma unroll
        for (int nb = 0; nb < 4; ++nb)
            bfr[nb] = *(const frag*)&Bs[(wn * 64 + nb * 16 + ll) * 40 + g * 8];
        #pragma unroll
        for (int mb = 0; mb < 4; ++mb)
            #pragma unroll
            for (int nb = 0; nb < 4; ++nb)
                acc[mb][nb] = MFMA(af[mb], bfr[nb], acc[mb][nb]);
        __syncthreads();
    }

    #pragma unroll
    for (int nb = 0; nb < 4; ++nb) {
        int col = col0 + wn * 64 + nb * 16 + ll;
        float bv = bias[col];
        #pragma unroll
        for (int mb = 0; mb < 4; ++mb) {
            #pragma unroll
            for (int r = 0; r < 4; ++r) {
                int row = row0 + wm * 64 + mb * 16 + g * 4 + r;
                float v = acc[mb][nb][r] + bv;
                float u2 = 1.5957691216f * v + 0.0713548162f * (v * v * v);
                float e = exp2f(u2 * LOG2E_);
                float rr = __builtin_amdgcn_rcpf(e + 1.0f);
                float gl = v - v * rr;
                Hout[(size_t)row * 1024 + col] = bf16b(gl);
            }
        }
    }
}

// ---------------------------------------------------------------------------
// GEMM2: X[16384,256] += A[16384,1024]_bf16 @ W^T-stored[256,1024] + b2
// ---------------------------------------------------------------------------
__global__ __launch_bounds__(256) void gemm2_kernel(
    const ushort* __restrict__ A, const ushort* __restrict__ Bt,
    const float* __restrict__ bias, float* __restrict__ X)
{
    __shared__ ushort As[128 * 40];
    __shared__ ushort Bs[128 * 40];
    const int tid = threadIdx.x;
    const int w = tid >> 6, l = tid & 63, g = l >> 4, ll = l & 15;
    const int wm = w >> 1, wn = w & 1;
    const int row0 = blockIdx.y * 128, col0 = blockIdx.x * 128;
    f32x4 acc[4][4] = {};

    for (int k0 = 0; k0 < 1024; k0 += 32) {
        #pragma unroll
        for (int i = 0; i < 2; ++i) {
            int cid = i * 256 + tid;
            int m = cid >> 2, c = cid & 3;
            *(uint4*)&As[m * 40 + c * 8] =
                *(const uint4*)(A + (size_t)(row0 + m) * 1024 + k0 + c * 8);
            *(uint4*)&Bs[m * 40 + c * 8] =
                *(const uint4*)(Bt + (size_t)(col0 + m) * 1024 + k0 + c * 8);
        }
        __syncthreads();
        frag af[4], bfr[4];
        #pragma unroll
        for (int mb = 0; mb < 4; ++mb)
            af[mb] = *(const frag*)&As[(wm * 64 + mb * 16 + ll) * 40 + g * 8];
        #pragma unroll
        for (int nb = 0; nb < 4; ++nb)
            bfr[nb] = *(const frag*)&Bs[(wn * 64 + nb * 16 + ll) * 40 + g * 8];
        #pragma unroll
        for (int mb = 0; mb < 4; ++mb)
            #pragma unroll
            for (int nb = 0; nb < 4; ++nb)
                acc[mb][nb] = MFMA(af[mb], bfr[nb], acc[mb][nb]);
        __syncthreads();
    }

    #pragma unroll
    for (int nb = 0; nb < 4; ++nb) {
        int col = col0 + wn * 64 + nb * 16 + ll;
        float bv = bias[col];
        #pragma unroll
        for (int mb = 0; mb < 4; ++mb) {
            #pragma unroll
            for (int r = 0; r < 4; ++r) {
                int row = row0 + wm * 64 + mb * 16 + g * 4 + r;
                float* xp = X + (size_t)row * 256 + col;
                *xp += acc[mb][nb][r] + bv;
            }
        }
    }
}

// ---------------------------------------------------------------------------
extern "C" void kernel_launch(void* const* d_in, const int* in_sizes, int n_in,
                              void* d_out, int out_size, void* d_ws, size_t ws_size,
                              hipStream_t stream)
{
    const int*   tokens  = (const int*)d_in[0];
    const int*   pos_ids = (const int*)d_in[1];
    const float* emb     = (const float*)d_in[2];
    const float* iw      = (const float*)d_in[3];
    const float* pw      = (const float*)d_in[4];
    const float* ln1w    = (const float*)d_in[5];
    const float* ln1b    = (const float*)d_in[6];
    const float* ln2w    = (const float*)d_in[7];
    const float* ln2b    = (const float*)d_in[8];
    const float* w1      = (const float*)d_in[9];
    const float* b1      = (const float*)d_in[10];
    const float* w2      = (const float*)d_in[11];
    const float* b2      = (const float*)d_in[12];
    const float* lnfw    = (const float*)d_in[13];
    const float* lnfb    = (const float*)d_in[14];

    float* x = (float*)d_out;                    // [B,S,D] f32 residual stream
    char* ws = (char*)d_ws;
    ushort* xn   = (ushort*)ws;                  // 8,388,608 B (attn head-packed OR mlp row-major)
    ushort* vti  = (ushort*)(ws + 8388608);      // 8,388,608 B [BH][32][S] interleaved
    ushort* hbuf = (ushort*)(ws + 16777216);     // 33,554,432 B
    ushort* w1t  = (ushort*)(ws + 50331648);     // 3,145,728 B  [L][1024][256]
    ushort* w2t  = (ushort*)(ws + 53477376);     // 3,145,728 B  [L][256][1024]

    wtr_kernel<<<dim3(32, 8, L_), 256, 0, stream>>>(w1, w1t, 256, 1024);
    wtr_kernel<<<dim3(8, 32, L_), 256, 0, stream>>>(w2, w2t, 1024, 256);

    embed_kernel<<<B_ * S_, 256, 0, stream>>>(tokens, pos_ids, emb, iw, pw, x);

    for (int l = 0; l < L_; l++) {
        ln_kernel<1><<<(B_ * S_) / 4, 256, 0, stream>>>(x, ln1w + l * D_, ln1b + l * D_, xn);
        vtr_kernel<<<dim3(S_ / 128, B_ * H_), 256, 0, stream>>>(xn, vti);
        attn_kernel<<<dim3(S_ / 64, B_ * H_), 256, 0, stream>>>(xn, vti, x);
        ln_kernel<2><<<(B_ * S_) / 4, 256, 0, stream>>>(x, ln2w + l * D_, ln2b + l * D_, xn);
        gemm1_kernel<<<dim3(H2_ / 128, (B_ * S_) / 128), 256, 0, stream>>>(
            xn, w1t + (size_t)l * D_ * H2_, b1 + (size_t)l * H2_, hbuf);
        gemm2_kernel<<<dim3(D_ / 128, (B_ * S_) / 128), 256, 0, stream>>>(
            hbuf, w2t + (size_t)l * H2_ * D_, b2 + (size_t)l * D_, x);
    }
    ln_kernel<0><<<(B_ * S_) / 4, 256, 0, stream>>>(x, lnfw, lnfb, x);
}

// Round 4
// 973.289 us; speedup vs baseline: 4.6341x; 1.0620x over previous
//
#include <hip/hip_runtime.h>
#include <hip/hip_bf16.h>
#include <math.h>

#define B_   16
#define S_   1024
#define D_   256
#define H_   8
#define HD_  32
#define L_   6
#define H2_  1024
#define LN_EPS 1e-5f
#define LOG2E_ 1.4426950408889634f
#define SCALE_ 0.17677669529663687f  // 1/sqrt(32)

typedef __attribute__((ext_vector_type(8))) short frag;    // 8 bf16 (4 VGPRs)
typedef __attribute__((ext_vector_type(4))) float f32x4;

#define MFMA(a, b, c) __builtin_amdgcn_mfma_f32_16x16x32_bf16((a), (b), (c), 0, 0, 0)

__device__ inline ushort bf16b(float f) {
    uint u = __builtin_bit_cast(uint, f);
    u += 0x7fff + ((u >> 16) & 1);       // RNE
    return (ushort)(u >> 16);
}
__device__ inline uint cvt_pk_bf16(float lo, float hi) {
    uint r;
    asm("v_cvt_pk_bf16_f32 %0, %1, %2" : "=v"(r) : "v"(lo), "v"(hi));
    return r;
}
// async global->LDS, 16B per lane (dest = wave-uniform base + lane*16)
__device__ __forceinline__ void gload16(const ushort* g, ushort* l) {
    __builtin_amdgcn_global_load_lds(
        (const __attribute__((address_space(1))) uint*)g,
        (__attribute__((address_space(3))) uint*)l, 16, 0, 0);
}

// ---------------------------------------------------------------------------
// Weight transpose + f32->bf16: in [K][N] f32 -> out [N][K] bf16 (per layer z)
// ---------------------------------------------------------------------------
__global__ __launch_bounds__(256) void wtr_kernel(
    const float* __restrict__ in, ushort* __restrict__ out, int K, int N)
{
    __shared__ ushort Ts[32][36];
    in  += (size_t)blockIdx.z * K * N;
    out += (size_t)blockIdx.z * K * N;
    int n0 = blockIdx.x * 32, k0 = blockIdx.y * 32;
    int r = threadIdx.x >> 3, c4 = (threadIdx.x & 7) * 4;
    float4 f = *(const float4*)(in + (size_t)(k0 + r) * N + n0 + c4);
    Ts[r][c4 + 0] = bf16b(f.x);
    Ts[r][c4 + 1] = bf16b(f.y);
    Ts[r][c4 + 2] = bf16b(f.z);
    Ts[r][c4 + 3] = bf16b(f.w);
    __syncthreads();
    ushort4 o = { Ts[c4 + 0][r], Ts[c4 + 1][r], Ts[c4 + 2][r], Ts[c4 + 3][r] };
    *(ushort4*)(out + (size_t)(n0 + r) * K + k0 + c4) = o;
}

// ---------------------------------------------------------------------------
// Embedding (f32 out)
// ---------------------------------------------------------------------------
__global__ __launch_bounds__(256) void embed_kernel(
    const int* __restrict__ tokens, const int* __restrict__ pos_ids,
    const float* __restrict__ emb, const float* __restrict__ iwp,
    const float* __restrict__ pwp, float* __restrict__ X)
{
    int bs = blockIdx.x;
    int s = bs & (S_ - 1);
    int d = threadIdx.x;
    int tok = tokens[bs];
    float p = (float)pos_ids[s];
    int j = (d < 128) ? d : (d - 128);
    float invf = exp2f(-(float)j * (13.287712379549449f / 128.0f));
    float ang = p * invf;
    float pe = (d < 128) ? sinf(ang) : cosf(ang);
    X[(size_t)bs * D_ + d] = iwp[0] * emb[tok * D_ + d] + pwp[0] * pe;
}

// ---------------------------------------------------------------------------
// LayerNorm: wave per row. MODE 0: f32 row-major. MODE 1: bf16 head-packed
// [B][H][S][32]. MODE 2: bf16 row-major [M][256].
// ---------------------------------------------------------------------------
template<int MODE>
__global__ __launch_bounds__(256) void ln_kernel(
    const float* __restrict__ X, const float* __restrict__ w,
    const float* __restrict__ b, void* __restrict__ outp)
{
    int row = blockIdx.x * 4 + (threadIdx.x >> 6);
    int lane = threadIdx.x & 63;
    const float4 v = *(const float4*)(X + (size_t)row * D_ + lane * 4);
    float s = v.x + v.y + v.z + v.w;
    #pragma unroll
    for (int m = 1; m < 64; m <<= 1) s += __shfl_xor(s, m, 64);
    float mu = s * (1.0f / 256.0f);
    float dx = v.x - mu, dy = v.y - mu, dz = v.z - mu, dw = v.w - mu;
    float vs = dx * dx + dy * dy + dz * dz + dw * dw;
    #pragma unroll
    for (int m = 1; m < 64; m <<= 1) vs += __shfl_xor(vs, m, 64);
    float inv = rsqrtf(vs * (1.0f / 256.0f) + LN_EPS);
    float4 wv = *(const float4*)(w + lane * 4);
    float4 bv = *(const float4*)(b + lane * 4);
    float o0 = dx * inv * wv.x + bv.x;
    float o1 = dy * inv * wv.y + bv.y;
    float o2 = dz * inv * wv.z + bv.z;
    float o3 = dw * inv * wv.w + bv.w;
    if constexpr (MODE == 0) {
        float4 o = { o0, o1, o2, o3 };
        *(float4*)((float*)outp + (size_t)row * D_ + lane * 4) = o;
    } else if constexpr (MODE == 1) {
        int bb = row >> 10, ss = row & 1023;
        int h = lane >> 3, dd = (lane & 7) * 4;
        ushort4 o = { bf16b(o0), bf16b(o1), bf16b(o2), bf16b(o3) };
        *(ushort4*)((ushort*)outp + (((size_t)(bb * H_ + h) * S_ + ss) * HD_ + dd)) = o;
    } else {
        ushort4 o = { bf16b(o0), bf16b(o1), bf16b(o2), bf16b(o3) };
        *(ushort4*)((ushort*)outp + (size_t)row * D_ + lane * 4) = o;
    }
}

// ---------------------------------------------------------------------------
// V transpose: XNB [bh][s][32] -> VTI [bh][d][s'] with per-32-block slot
// interleave col(s) = 2*(s&15) + ((s>>4)&1), matching P packing.
// ---------------------------------------------------------------------------
__global__ __launch_bounds__(256) void vtr_kernel(
    const ushort* __restrict__ XNB, ushort* __restrict__ VTI)
{
    __shared__ ushort Ts[32][136];
    const int bh = blockIdx.y;
    const int sblk = blockIdx.x * 128;
    const ushort* __restrict__ base = XNB + (size_t)bh * (S_ * HD_);
    #pragma unroll
    for (int i = 0; i < 2; ++i) {
        int cid = i * 256 + threadIdx.x;
        int s = cid >> 2, c = cid & 3;
        uint4 u = *(const uint4*)(base + (size_t)(sblk + s) * HD_ + c * 8);
        int col = ((s >> 5) << 5) + 2 * (s & 15) + ((s >> 4) & 1);
        int d0 = c * 8;
        Ts[d0 + 0][col] = (ushort)(u.x & 0xffff);
        Ts[d0 + 1][col] = (ushort)(u.x >> 16);
        Ts[d0 + 2][col] = (ushort)(u.y & 0xffff);
        Ts[d0 + 3][col] = (ushort)(u.y >> 16);
        Ts[d0 + 4][col] = (ushort)(u.z & 0xffff);
        Ts[d0 + 5][col] = (ushort)(u.z >> 16);
        Ts[d0 + 6][col] = (ushort)(u.w & 0xffff);
        Ts[d0 + 7][col] = (ushort)(u.w >> 16);
    }
    __syncthreads();
    #pragma unroll
    for (int i = 0; i < 2; ++i) {
        int cid = i * 256 + threadIdx.x;
        int d = cid >> 4, ch = cid & 15;
        uint4 o = *(const uint4*)&Ts[d][ch * 8];
        *(uint4*)(VTI + ((size_t)bh * HD_ + d) * S_ + sblk + ch * 8) = o;
    }
}

// ---------------------------------------------------------------------------
// Flash attention, bf16 MFMA, 64-key rounds, NO-MAX softmax (scores bounded:
// LN-normalized q,k and diagonal term guarantee os >= 1, exp2 args |.|<~64).
// Bias: closed-form incremental — xq wave-constant, yt round-constant:
//   dist = dyv[r][j&1] + |xqc - 2it - (j>>1)|, slope uniform except it==bx.
// 4 waves x 16 q-rows, no barriers. grid (S/64, B*H).
// ---------------------------------------------------------------------------
__global__ __launch_bounds__(256) void attn_kernel(
    const ushort* __restrict__ XNB, const ushort* __restrict__ VTI,
    float* __restrict__ X)
{
    __shared__ ushort Pl[4][16][72];   // per-wave P: 16 rows x 64 slots (+pad)

    const int bh = blockIdx.y;
    const int b = bh >> 3, h = bh & 7;
    const ushort* __restrict__ base = XNB + (size_t)bh * (S_ * HD_);
    const ushort* __restrict__ vbase = VTI + (size_t)bh * (HD_ * S_);
    const int tid = threadIdx.x;
    const int w = tid >> 6, l = tid & 63, g = l >> 4, ll = l & 15;
    const int bx = blockIdx.x;
    const int q0 = bx * 64 + w * 16;

    const float C1 = SCALE_ * LOG2E_;
    // Q fragment, pre-scaled by C1 (folds the softmax scale + log2e into QK^T)
    frag qf = *(const frag*)(base + (size_t)(q0 + ll) * HD_ + g * 8);
    #pragma unroll
    for (int i = 0; i < 8; ++i) {
        float f = __builtin_bit_cast(float, ((uint)(ushort)qf[i]) << 16);
        qf[i] = (short)bf16b(f * C1);
    }

    const float slr = -exp2f(-(0.5f + (float)h)) * LOG2E_;
    const float sll = -exp2f(-(1.0f + (float)h)) * LOG2E_;

    int qr[4], yq[4];
    const int xqc = q0 >> 5;             // wave-constant
    #pragma unroll
    for (int r = 0; r < 4; ++r) { qr[r] = q0 + g * 4 + r; yq[r] = qr[r] & 31; }

    float dyv[4][2];                     // |yq[r] - yt|, yt = p*16 + ll
    #pragma unroll
    for (int r = 0; r < 4; ++r) {
        dyv[r][0] = (float)abs(yq[r] - ll);
        dyv[r][1] = (float)abs(yq[r] - (16 + ll));
    }

    f32x4 o0 = { 0.f, 0.f, 0.f, 0.f };
    f32x4 o1 = { 0.f, 0.f, 0.f, 0.f };
    f32x4 os = { 0.f, 0.f, 0.f, 0.f };
    const f32x4 zc = { 0.f, 0.f, 0.f, 0.f };
    const short one_s = (short)0x3F80;
    const frag ones = { one_s, one_s, one_s, one_s, one_s, one_s, one_s, one_s };

    frag kf0 = *(const frag*)(base + (size_t)(ll)      * HD_ + g * 8);
    frag kf1 = *(const frag*)(base + (size_t)(16 + ll) * HD_ + g * 8);
    frag kf2 = *(const frag*)(base + (size_t)(32 + ll) * HD_ + g * 8);
    frag kf3 = *(const frag*)(base + (size_t)(48 + ll) * HD_ + g * 8);

    for (int it = 0; it < 16; ++it) {
        const int tb = it * 64;
        const int nt = (it < 15) ? tb + 64 : tb;
        frag nk0 = *(const frag*)(base + (size_t)(nt + ll)      * HD_ + g * 8);
        frag nk1 = *(const frag*)(base + (size_t)(nt + 16 + ll) * HD_ + g * 8);
        frag nk2 = *(const frag*)(base + (size_t)(nt + 32 + ll) * HD_ + g * 8);
        frag nk3 = *(const frag*)(base + (size_t)(nt + 48 + ll) * HD_ + g * 8);
        frag vf0 = *(const frag*)(vbase + (size_t)(ll)      * S_ + tb + g * 8);
        frag vf1 = *(const frag*)(vbase + (size_t)(16 + ll) * S_ + tb + g * 8);
        frag vf2 = *(const frag*)(vbase + (size_t)(ll)      * S_ + tb + 32 + g * 8);
        frag vf3 = *(const frag*)(vbase + (size_t)(16 + ll) * S_ + tb + 32 + g * 8);

        f32x4 sa[4];
        sa[0] = MFMA(qf, kf0, zc);
        sa[1] = MFMA(qf, kf1, zc);
        sa[2] = MFMA(qf, kf2, zc);
        sa[3] = MFMA(qf, kf3, zc);

        float vv[4][4];
        if (it == bx) {
            // boundary round: exact per-score slope + distance
            #pragma unroll
            for (int j = 0; j < 4; ++j) {
                int tg = tb + j * 16 + ll;
                int xt = tg >> 5, yt = tg & 31;
                #pragma unroll
                for (int r = 0; r < 4; ++r) {
                    int dist = abs(xqc - xt) + abs(yq[r] - yt);
                    float sl = (tg > qr[r]) ? slr : sll;
                    vv[r][j] = fmaf(sl, (float)dist, sa[j][r]);
                }
            }
        } else {
            float ax0 = (float)abs(xqc - 2 * it);
            float ax1 = (float)abs(xqc - 2 * it - 1);
            float sl = (it > bx) ? slr : sll;
            #pragma unroll
            for (int j = 0; j < 4; ++j) {
                float axc = (j >> 1) ? ax1 : ax0;
                #pragma unroll
                for (int r = 0; r < 4; ++r)
                    vv[r][j] = fmaf(sl, dyv[r][j & 1] + axc, sa[j][r]);
            }
        }
        #pragma unroll
        for (int r = 0; r < 4; ++r) {
            float e0 = exp2f(vv[r][0]);
            float e1 = exp2f(vv[r][1]);
            float e2 = exp2f(vv[r][2]);
            float e3 = exp2f(vv[r][3]);
            *(uint*)&Pl[w][g * 4 + r][2 * ll]      = cvt_pk_bf16(e0, e1);
            *(uint*)&Pl[w][g * 4 + r][32 + 2 * ll] = cvt_pk_bf16(e2, e3);
        }
        frag pf0 = *(const frag*)&Pl[w][ll][g * 8];
        frag pf1 = *(const frag*)&Pl[w][ll][32 + g * 8];
        o0 = MFMA(pf0, vf0, o0);
        o1 = MFMA(pf0, vf1, o1);
        os = MFMA(pf0, ones, os);
        o0 = MFMA(pf1, vf2, o0);
        o1 = MFMA(pf1, vf3, o1);
        os = MFMA(pf1, ones, os);
        kf0 = nk0; kf1 = nk1; kf2 = nk2; kf3 = nk3;
    }

    #pragma unroll
    for (int r = 0; r < 4; ++r) {
        float inv = 1.0f / os[r];
        float* xp = X + ((size_t)(b * S_ + qr[r])) * D_ + h * HD_;
        xp[ll]      += o0[r] * inv;
        xp[16 + ll] += o1[r] * inv;
    }
}

// ---------------------------------------------------------------------------
// GEMM1: H[16384,1024] = GELU(A[16384,256]_bf16 @ W^T[1024,256] + b1), bf16 out
// m97 structure: global_load_lds dwordx4 -> linear [128][32] LDS, 2 barriers.
// ---------------------------------------------------------------------------
__global__ __launch_bounds__(256) void gemm1_kernel(
    const ushort* __restrict__ A, const ushort* __restrict__ Bt,
    const float* __restrict__ bias, ushort* __restrict__ Hout)
{
    __shared__ ushort As[128 * 32];
    __shared__ ushort Bs[128 * 32];
    const int tid = threadIdx.x;
    const int w = tid >> 6, l = tid & 63, g = l >> 4, ll = l & 15;
    const int wm = w >> 1, wn = w & 1;
    const int row0 = blockIdx.y * 128, col0 = blockIdx.x * 128;

    const int srow = w * 32 + (l >> 2);          // staged row (j adds +16)
    const int scol = (l & 3) * 8;                // ushort col within 32
    const ushort* ga = A  + (size_t)(row0 + srow) * 256 + scol;
    const ushort* gb = Bt + (size_t)(col0 + srow) * 256 + scol;
    ushort* lA = &As[w * 1024 + l * 8];
    ushort* lB = &Bs[w * 1024 + l * 8];

    f32x4 acc[4][4] = {};
    for (int k0 = 0; k0 < 256; k0 += 32) {
        __syncthreads();
        gload16(ga + k0,            lA);
        gload16(ga + k0 + 16 * 256, lA + 512);
        gload16(gb + k0,            lB);
        gload16(gb + k0 + 16 * 256, lB + 512);
        __syncthreads();
        frag af[4], bfr[4];
        #pragma unroll
        for (int mb = 0; mb < 4; ++mb)
            af[mb] = *(const frag*)&As[(wm * 64 + mb * 16 + ll) * 32 + g * 8];
        #pragma unroll
        for (int nb = 0; nb < 4; ++nb)
            bfr[nb] = *(const frag*)&Bs[(wn * 64 + nb * 16 + ll) * 32 + g * 8];
        #pragma unroll
        for (int mb = 0; mb < 4; ++mb)
            #pragma unroll
            for (int nb = 0; nb < 4; ++nb)
                acc[mb][nb] = MFMA(af[mb], bfr[nb], acc[mb][nb]);
    }

    #pragma unroll
    for (int nb = 0; nb < 4; ++nb) {
        int col = col0 + wn * 64 + nb * 16 + ll;
        float bv = bias[col];
        #pragma unroll
        for (int mb = 0; mb < 4; ++mb) {
            #pragma unroll
            for (int r = 0; r < 4; ++r) {
                int row = row0 + wm * 64 + mb * 16 + g * 4 + r;
                float v = acc[mb][nb][r] + bv;
                float u2 = 1.5957691216f * v + 0.0713548162f * (v * v * v);
                float e = exp2f(u2 * LOG2E_);
                float rr = __builtin_amdgcn_rcpf(e + 1.0f);
                float gl = v - v * rr;
                Hout[(size_t)row * 1024 + col] = bf16b(gl);
            }
        }
    }
}

// ---------------------------------------------------------------------------
// GEMM2: X[16384,256] += A[16384,1024]_bf16 @ W^T[256,1024] + b2
// 128(M)x64(N) tile, 4 waves (wave = 32 rows x 64 cols), K=1024.
// grid (4, 128) = 512 blocks = 2/CU.
// ---------------------------------------------------------------------------
__global__ __launch_bounds__(256) void gemm2_kernel(
    const ushort* __restrict__ A, const ushort* __restrict__ Bt,
    const float* __restrict__ bias, float* __restrict__ X)
{
    __shared__ ushort As[128 * 32];
    __shared__ ushort Bs[64 * 32];
    const int tid = threadIdx.x;
    const int w = tid >> 6, l = tid & 63, g = l >> 4, ll = l & 15;
    const int row0 = blockIdx.y * 128, col0 = blockIdx.x * 64;

    const int srow = w * 32 + (l >> 2);
    const int scol = (l & 3) * 8;
    const ushort* ga = A  + (size_t)(row0 + srow) * 1024 + scol;
    const ushort* gb = Bt + (size_t)(col0 + w * 16 + (l >> 2)) * 1024 + scol;
    ushort* lA = &As[w * 1024 + l * 8];
    ushort* lB = &Bs[w * 512 + l * 8];

    f32x4 acc[2][4] = {};
    for (int k0 = 0; k0 < 1024; k0 += 32) {
        __syncthreads();
        gload16(ga + k0,             lA);
        gload16(ga + k0 + 16 * 1024, lA + 512);
        gload16(gb + k0,             lB);
        __syncthreads();
        frag af[2], bfr[4];
        #pragma unroll
        for (int mb = 0; mb < 2; ++mb)
            af[mb] = *(const frag*)&As[(w * 32 + mb * 16 + ll) * 32 + g * 8];
        #pragma unroll
        for (int nb = 0; nb < 4; ++nb)
            bfr[nb] = *(const frag*)&Bs[(nb * 16 + ll) * 32 + g * 8];
        #pragma unroll
        for (int mb = 0; mb < 2; ++mb)
            #pragma unroll
            for (int nb = 0; nb < 4; ++nb)
                acc[mb][nb] = MFMA(af[mb], bfr[nb], acc[mb][nb]);
    }

    #pragma unroll
    for (int nb = 0; nb < 4; ++nb) {
        int col = col0 + nb * 16 + ll;
        float bv = bias[col];
        #pragma unroll
        for (int mb = 0; mb < 2; ++mb) {
            #pragma unroll
            for (int r = 0; r < 4; ++r) {
                int row = row0 + w * 32 + mb * 16 + g * 4 + r;
                float* xp = X + (size_t)row * 256 + col;
                *xp += acc[mb][nb][r] + bv;
            }
        }
    }
}

// ---------------------------------------------------------------------------
extern "C" void kernel_launch(void* const* d_in, const int* in_sizes, int n_in,
                              void* d_out, int out_size, void* d_ws, size_t ws_size,
                              hipStream_t stream)
{
    const int*   tokens  = (const int*)d_in[0];
    const int*   pos_ids = (const int*)d_in[1];
    const float* emb     = (const float*)d_in[2];
    const float* iw      = (const float*)d_in[3];
    const float* pw      = (const float*)d_in[4];
    const float* ln1w    = (const float*)d_in[5];
    const float* ln1b    = (const float*)d_in[6];
    const float* ln2w    = (const float*)d_in[7];
    const float* ln2b    = (const float*)d_in[8];
    const float* w1      = (const float*)d_in[9];
    const float* b1      = (const float*)d_in[10];
    const float* w2      = (const float*)d_in[11];
    const float* b2      = (const float*)d_in[12];
    const float* lnfw    = (const float*)d_in[13];
    const float* lnfb    = (const float*)d_in[14];

    float* x = (float*)d_out;                    // [B,S,D] f32 residual stream
    char* ws = (char*)d_ws;
    ushort* xn   = (ushort*)ws;                  // 8,388,608 B
    ushort* vti  = (ushort*)(ws + 8388608);      // 8,388,608 B
    ushort* hbuf = (ushort*)(ws + 16777216);     // 33,554,432 B
    ushort* w1t  = (ushort*)(ws + 50331648);     // 3,145,728 B  [L][1024][256]
    ushort* w2t  = (ushort*)(ws + 53477376);     // 3,145,728 B  [L][256][1024]

    wtr_kernel<<<dim3(32, 8, L_), 256, 0, stream>>>(w1, w1t, 256, 1024);
    wtr_kernel<<<dim3(8, 32, L_), 256, 0, stream>>>(w2, w2t, 1024, 256);

    embed_kernel<<<B_ * S_, 256, 0, stream>>>(tokens, pos_ids, emb, iw, pw, x);

    for (int l = 0; l < L_; l++) {
        ln_kernel<1><<<(B_ * S_) / 4, 256, 0, stream>>>(x, ln1w + l * D_, ln1b + l * D_, xn);
        vtr_kernel<<<dim3(S_ / 128, B_ * H_), 256, 0, stream>>>(xn, vti);
        attn_kernel<<<dim3(S_ / 64, B_ * H_), 256, 0, stream>>>(xn, vti, x);
        ln_kernel<2><<<(B_ * S_) / 4, 256, 0, stream>>>(x, ln2w + l * D_, ln2b + l * D_, xn);
        gemm1_kernel<<<dim3(H2_ / 128, (B_ * S_) / 128), 256, 0, stream>>>(
            xn, w1t + (size_t)l * D_ * H2_, b1 + (size_t)l * H2_, hbuf);
        gemm2_kernel<<<dim3(D_ / 64, (B_ * S_) / 128), 256, 0, stream>>>(
            hbuf, w2t + (size_t)l * H2_ * D_, b2 + (size_t)l * D_, x);
    }
    ln_kernel<0><<<(B_ * S_) / 4, 256, 0, stream>>>(x, lnfw, lnfb, x);
}

// Round 5
// 969.602 us; speedup vs baseline: 4.6517x; 1.0038x over previous
//
#include <hip/hip_runtime.h>
#include <hip/hip_bf16.h>
#include <math.h>

#define B_   16
#define S_   1024
#define D_   256
#define H_   8
#define HD_  32
#define L_   6
#define H2_  1024
#define LN_EPS 1e-5f
#define LOG2E_ 1.4426950408889634f
#define SCALE_ 0.17677669529663687f  // 1/sqrt(32)

typedef __attribute__((ext_vector_type(8))) short frag;    // 8 bf16 (4 VGPRs)
typedef __attribute__((ext_vector_type(4))) float f32x4;

#define MFMA(a, b, c) __builtin_amdgcn_mfma_f32_16x16x32_bf16((a), (b), (c), 0, 0, 0)

__device__ inline ushort bf16b(float f) {
    uint u = __builtin_bit_cast(uint, f);
    u += 0x7fff + ((u >> 16) & 1);       // RNE
    return (ushort)(u >> 16);
}
__device__ inline uint cvt_pk_bf16(float lo, float hi) {
    uint r;
    asm("v_cvt_pk_bf16_f32 %0, %1, %2" : "=v"(r) : "v"(lo), "v"(hi));
    return r;
}
// async global->LDS, 16B per lane (dest = wave-uniform base + lane*16)
__device__ __forceinline__ void gload16(const ushort* g, ushort* l) {
    __builtin_amdgcn_global_load_lds(
        (const __attribute__((address_space(1))) uint*)g,
        (__attribute__((address_space(3))) uint*)l, 16, 0, 0);
}

// ---------------------------------------------------------------------------
// Weight transpose + f32->bf16: in [K][N] f32 -> out [N][K] bf16 (per layer z)
// ---------------------------------------------------------------------------
__global__ __launch_bounds__(256) void wtr_kernel(
    const float* __restrict__ in, ushort* __restrict__ out, int K, int N)
{
    __shared__ ushort Ts[32][36];
    in  += (size_t)blockIdx.z * K * N;
    out += (size_t)blockIdx.z * K * N;
    int n0 = blockIdx.x * 32, k0 = blockIdx.y * 32;
    int r = threadIdx.x >> 3, c4 = (threadIdx.x & 7) * 4;
    float4 f = *(const float4*)(in + (size_t)(k0 + r) * N + n0 + c4);
    Ts[r][c4 + 0] = bf16b(f.x);
    Ts[r][c4 + 1] = bf16b(f.y);
    Ts[r][c4 + 2] = bf16b(f.z);
    Ts[r][c4 + 3] = bf16b(f.w);
    __syncthreads();
    ushort4 o = { Ts[c4 + 0][r], Ts[c4 + 1][r], Ts[c4 + 2][r], Ts[c4 + 3][r] };
    *(ushort4*)(out + (size_t)(n0 + r) * K + k0 + c4) = o;
}

// ---------------------------------------------------------------------------
// Embedding (f32 out)
// ---------------------------------------------------------------------------
__global__ __launch_bounds__(256) void embed_kernel(
    const int* __restrict__ tokens, const int* __restrict__ pos_ids,
    const float* __restrict__ emb, const float* __restrict__ iwp,
    const float* __restrict__ pwp, float* __restrict__ X)
{
    int bs = blockIdx.x;
    int s = bs & (S_ - 1);
    int d = threadIdx.x;
    int tok = tokens[bs];
    float p = (float)pos_ids[s];
    int j = (d < 128) ? d : (d - 128);
    float invf = exp2f(-(float)j * (13.287712379549449f / 128.0f));
    float ang = p * invf;
    float pe = (d < 128) ? sinf(ang) : cosf(ang);
    X[(size_t)bs * D_ + d] = iwp[0] * emb[tok * D_ + d] + pwp[0] * pe;
}

// ---------------------------------------------------------------------------
// LayerNorm: wave per row. MODE 0: f32 row-major. MODE 1: bf16 head-packed
// [B][H][S][32]. MODE 2: bf16 row-major [M][256].
// ---------------------------------------------------------------------------
template<int MODE>
__global__ __launch_bounds__(256) void ln_kernel(
    const float* __restrict__ X, const float* __restrict__ w,
    const float* __restrict__ b, void* __restrict__ outp)
{
    int row = blockIdx.x * 4 + (threadIdx.x >> 6);
    int lane = threadIdx.x & 63;
    const float4 v = *(const float4*)(X + (size_t)row * D_ + lane * 4);
    float s = v.x + v.y + v.z + v.w;
    #pragma unroll
    for (int m = 1; m < 64; m <<= 1) s += __shfl_xor(s, m, 64);
    float mu = s * (1.0f / 256.0f);
    float dx = v.x - mu, dy = v.y - mu, dz = v.z - mu, dw = v.w - mu;
    float vs = dx * dx + dy * dy + dz * dz + dw * dw;
    #pragma unroll
    for (int m = 1; m < 64; m <<= 1) vs += __shfl_xor(vs, m, 64);
    float inv = rsqrtf(vs * (1.0f / 256.0f) + LN_EPS);
    float4 wv = *(const float4*)(w + lane * 4);
    float4 bv = *(const float4*)(b + lane * 4);
    float o0 = dx * inv * wv.x + bv.x;
    float o1 = dy * inv * wv.y + bv.y;
    float o2 = dz * inv * wv.z + bv.z;
    float o3 = dw * inv * wv.w + bv.w;
    if constexpr (MODE == 0) {
        float4 o = { o0, o1, o2, o3 };
        *(float4*)((float*)outp + (size_t)row * D_ + lane * 4) = o;
    } else if constexpr (MODE == 1) {
        int bb = row >> 10, ss = row & 1023;
        int h = lane >> 3, dd = (lane & 7) * 4;
        ushort4 o = { bf16b(o0), bf16b(o1), bf16b(o2), bf16b(o3) };
        *(ushort4*)((ushort*)outp + (((size_t)(bb * H_ + h) * S_ + ss) * HD_ + dd)) = o;
    } else {
        ushort4 o = { bf16b(o0), bf16b(o1), bf16b(o2), bf16b(o3) };
        *(ushort4*)((ushort*)outp + (size_t)row * D_ + lane * 4) = o;
    }
}

// ---------------------------------------------------------------------------
// V transpose: XNB [bh][s][32] -> VTI [bh][d][s'] with per-64-block key
// permutation sigma(t) = 32*(j&1) + 8*g + 4*(j>>1) + r, t = 16j + 4g + r.
// This makes exp2'd swapped-QK scores directly the PV A-fragment.
// ---------------------------------------------------------------------------
__global__ __launch_bounds__(256) void vtr_kernel(
    const ushort* __restrict__ XNB, ushort* __restrict__ VTI)
{
    __shared__ ushort Ts[32][136];
    const int bh = blockIdx.y;
    const int sblk = blockIdx.x * 128;
    const ushort* __restrict__ base = XNB + (size_t)bh * (S_ * HD_);
    #pragma unroll
    for (int i = 0; i < 2; ++i) {
        int cid = i * 256 + threadIdx.x;
        int s = cid >> 2, c = cid & 3;
        uint4 u = *(const uint4*)(base + (size_t)(sblk + s) * HD_ + c * 8);
        int col = (s & ~63) + 32 * ((s >> 4) & 1) + 8 * ((s >> 2) & 3)
                + 4 * ((s >> 5) & 1) + (s & 3);
        int d0 = c * 8;
        Ts[d0 + 0][col] = (ushort)(u.x & 0xffff);
        Ts[d0 + 1][col] = (ushort)(u.x >> 16);
        Ts[d0 + 2][col] = (ushort)(u.y & 0xffff);
        Ts[d0 + 3][col] = (ushort)(u.y >> 16);
        Ts[d0 + 4][col] = (ushort)(u.z & 0xffff);
        Ts[d0 + 5][col] = (ushort)(u.z >> 16);
        Ts[d0 + 6][col] = (ushort)(u.w & 0xffff);
        Ts[d0 + 7][col] = (ushort)(u.w >> 16);
    }
    __syncthreads();
    #pragma unroll
    for (int i = 0; i < 2; ++i) {
        int cid = i * 256 + threadIdx.x;
        int d = cid >> 4, ch = cid & 15;
        uint4 o = *(const uint4*)&Ts[d][ch * 8];
        *(uint4*)(VTI + ((size_t)bh * HD_ + d) * S_ + sblk + ch * 8) = o;
    }
}

// ---------------------------------------------------------------------------
// Flash attention, bf16 MFMA, 64-key rounds, swapped QK^T (A=K, B=Q) so each
// lane's 16 scores live on a single q-row (q = ll) at keys tb+16j+4g+r.
// With the sigma V-interleave, exp2'd scores pack (cvt_pk) DIRECTLY into the
// PV A-fragment: zero LDS, zero cross-lane ops, no-max softmax (bounded).
// XCD-locality: 1D grid, all 16 q-blocks of a bh on one XCD.
// ---------------------------------------------------------------------------
__global__ __launch_bounds__(256) void attn_kernel(
    const ushort* __restrict__ XNB, const ushort* __restrict__ VTI,
    float* __restrict__ X)
{
    // ---- XCD-locality remap: xcd = bi&7 (dispatch round-robin heuristic) ----
    const int bi = blockIdx.x;
    const int xcd = bi & 7, m = bi >> 3;          // m in [0,256)
    const int bh = xcd * 16 + (m >> 4);           // 16 bh per XCD
    const int bx = m & 15;                        // q-block within bh
    const int b = bh >> 3, h = bh & 7;

    const ushort* __restrict__ base = XNB + (size_t)bh * (S_ * HD_);
    const ushort* __restrict__ vbase = VTI + (size_t)bh * (HD_ * S_);
    const int tid = threadIdx.x;
    const int w = tid >> 6, l = tid & 63, g = l >> 4, ll = l & 15;
    const int q0 = bx * 64 + w * 16;
    const int qg = q0 + ll;                       // lane's q-row
    const int xq = qg >> 5, yq = qg & 31;

    const float C1 = SCALE_ * LOG2E_;
    // Q fragment (row qg), pre-scaled by C1
    frag qf = *(const frag*)(base + (size_t)qg * HD_ + g * 8);
    #pragma unroll
    for (int i = 0; i < 8; ++i) {
        float f = __builtin_bit_cast(float, ((uint)(ushort)qf[i]) << 16);
        qf[i] = (short)bf16b(f * C1);
    }

    const float slr = -exp2f(-(0.5f + (float)h)) * LOG2E_;
    const float sll = -exp2f(-(1.0f + (float)h)) * LOG2E_;

    // dy[p][r] = |yq - (16p + 4g + r)|  (round-constant)
    float dy[2][4];
    #pragma unroll
    for (int p = 0; p < 2; ++p)
        #pragma unroll
        for (int r = 0; r < 4; ++r)
            dy[p][r] = (float)abs(yq - (16 * p + 4 * g + r));

    f32x4 o0 = { 0.f, 0.f, 0.f, 0.f };
    f32x4 o1 = { 0.f, 0.f, 0.f, 0.f };
    f32x4 os = { 0.f, 0.f, 0.f, 0.f };
    const f32x4 zc = { 0.f, 0.f, 0.f, 0.f };
    const short one_s = (short)0x3F80;
    const frag ones = { one_s, one_s, one_s, one_s, one_s, one_s, one_s, one_s };

    frag kf0 = *(const frag*)(base + (size_t)(ll)      * HD_ + g * 8);
    frag kf1 = *(const frag*)(base + (size_t)(16 + ll) * HD_ + g * 8);
    frag kf2 = *(const frag*)(base + (size_t)(32 + ll) * HD_ + g * 8);
    frag kf3 = *(const frag*)(base + (size_t)(48 + ll) * HD_ + g * 8);

    for (int it = 0; it < 16; ++it) {
        const int tb = it * 64;
        const int nt = (it < 15) ? tb + 64 : tb;
        frag nk0 = *(const frag*)(base + (size_t)(nt + ll)      * HD_ + g * 8);
        frag nk1 = *(const frag*)(base + (size_t)(nt + 16 + ll) * HD_ + g * 8);
        frag nk2 = *(const frag*)(base + (size_t)(nt + 32 + ll) * HD_ + g * 8);
        frag nk3 = *(const frag*)(base + (size_t)(nt + 48 + ll) * HD_ + g * 8);
        frag vf0 = *(const frag*)(vbase + (size_t)(ll)      * S_ + tb + g * 8);
        frag vf1 = *(const frag*)(vbase + (size_t)(16 + ll) * S_ + tb + g * 8);
        frag vf2 = *(const frag*)(vbase + (size_t)(ll)      * S_ + tb + 32 + g * 8);
        frag vf3 = *(const frag*)(vbase + (size_t)(16 + ll) * S_ + tb + 32 + g * 8);

        // swapped: D[key][q] -> lane (g,ll): q = qg, keys tb + 16j + 4g + r
        f32x4 sa0 = MFMA(kf0, qf, zc);
        f32x4 sa1 = MFMA(kf1, qf, zc);
        f32x4 sa2 = MFMA(kf2, qf, zc);
        f32x4 sa3 = MFMA(kf3, qf, zc);

        float e0[4], e1[4], e2[4], e3[4];
        if (it == bx) {
            // boundary round: per-score slope (dist closed-form is exact always)
            const int kb = tb + 4 * g;
            #pragma unroll
            for (int r = 0; r < 4; ++r) {
                float sl0 = (kb + r      > qg) ? slr : sll;
                float sl1 = (kb + 16 + r > qg) ? slr : sll;
                float sl2 = (kb + 32 + r > qg) ? slr : sll;
                float sl3 = (kb + 48 + r > qg) ? slr : sll;
                float ax0 = (float)abs(xq - 2 * it);
                float ax1 = (float)abs(xq - 2 * it - 1);
                e0[r] = exp2f(fmaf(sl0, dy[0][r] + ax0, sa0[r]));
                e1[r] = exp2f(fmaf(sl1, dy[1][r] + ax0, sa1[r]));
                e2[r] = exp2f(fmaf(sl2, dy[0][r] + ax1, sa2[r]));
                e3[r] = exp2f(fmaf(sl3, dy[1][r] + ax1, sa3[r]));
            }
        } else {
            const float sl = (it > bx) ? slr : sll;
            const float ax0 = (float)abs(xq - 2 * it);
            const float ax1 = (float)abs(xq - 2 * it - 1);
            #pragma unroll
            for (int r = 0; r < 4; ++r) {
                e0[r] = exp2f(fmaf(sl, dy[0][r] + ax0, sa0[r]));
                e1[r] = exp2f(fmaf(sl, dy[1][r] + ax0, sa1[r]));
                e2[r] = exp2f(fmaf(sl, dy[0][r] + ax1, sa2[r]));
                e3[r] = exp2f(fmaf(sl, dy[1][r] + ax1, sa3[r]));
            }
        }
        // pack directly into PV A-frags: pf0 = keys slots 0-31, pf1 = 32-63
        uint4 p0u = { cvt_pk_bf16(e0[0], e0[1]), cvt_pk_bf16(e0[2], e0[3]),
                      cvt_pk_bf16(e2[0], e2[1]), cvt_pk_bf16(e2[2], e2[3]) };
        uint4 p1u = { cvt_pk_bf16(e1[0], e1[1]), cvt_pk_bf16(e1[2], e1[3]),
                      cvt_pk_bf16(e3[0], e3[1]), cvt_pk_bf16(e3[2], e3[3]) };
        frag pf0 = __builtin_bit_cast(frag, p0u);
        frag pf1 = __builtin_bit_cast(frag, p1u);

        o0 = MFMA(pf0, vf0, o0);
        o1 = MFMA(pf0, vf1, o1);
        os = MFMA(pf0, ones, os);
        o0 = MFMA(pf1, vf2, o0);
        o1 = MFMA(pf1, vf3, o1);
        os = MFMA(pf1, ones, os);
        kf0 = nk0; kf1 = nk1; kf2 = nk2; kf3 = nk3;
    }

    #pragma unroll
    for (int r = 0; r < 4; ++r) {
        int qr = q0 + g * 4 + r;
        float inv = 1.0f / os[r];
        float* xp = X + ((size_t)(b * S_ + qr)) * D_ + h * HD_;
        xp[ll]      += o0[r] * inv;
        xp[16 + ll] += o1[r] * inv;
    }
}

// ---------------------------------------------------------------------------
// GEMM1: H[16384,1024] = GELU(A[16384,256]_bf16 @ W^T[1024,256] + b1), bf16 out
// m97 structure: global_load_lds dwordx4 -> linear [128][32] LDS, 2 barriers.
// ---------------------------------------------------------------------------
__global__ __launch_bounds__(256) void gemm1_kernel(
    const ushort* __restrict__ A, const ushort* __restrict__ Bt,
    const float* __restrict__ bias, ushort* __restrict__ Hout)
{
    __shared__ ushort As[128 * 32];
    __shared__ ushort Bs[128 * 32];
    const int tid = threadIdx.x;
    const int w = tid >> 6, l = tid & 63, g = l >> 4, ll = l & 15;
    const int wm = w >> 1, wn = w & 1;
    const int row0 = blockIdx.y * 128, col0 = blockIdx.x * 128;

    const int srow = w * 32 + (l >> 2);
    const int scol = (l & 3) * 8;
    const ushort* ga = A  + (size_t)(row0 + srow) * 256 + scol;
    const ushort* gb = Bt + (size_t)(col0 + srow) * 256 + scol;
    ushort* lA = &As[w * 1024 + l * 8];
    ushort* lB = &Bs[w * 1024 + l * 8];

    f32x4 acc[4][4] = {};
    for (int k0 = 0; k0 < 256; k0 += 32) {
        __syncthreads();
        gload16(ga + k0,            lA);
        gload16(ga + k0 + 16 * 256, lA + 512);
        gload16(gb + k0,            lB);
        gload16(gb + k0 + 16 * 256, lB + 512);
        __syncthreads();
        frag af[4], bfr[4];
        #pragma unroll
        for (int mb = 0; mb < 4; ++mb)
            af[mb] = *(const frag*)&As[(wm * 64 + mb * 16 + ll) * 32 + g * 8];
        #pragma unroll
        for (int nb = 0; nb < 4; ++nb)
            bfr[nb] = *(const frag*)&Bs[(wn * 64 + nb * 16 + ll) * 32 + g * 8];
        #pragma unroll
        for (int mb = 0; mb < 4; ++mb)
            #pragma unroll
            for (int nb = 0; nb < 4; ++nb)
                acc[mb][nb] = MFMA(af[mb], bfr[nb], acc[mb][nb]);
    }

    #pragma unroll
    for (int nb = 0; nb < 4; ++nb) {
        int col = col0 + wn * 64 + nb * 16 + ll;
        float bv = bias[col];
        #pragma unroll
        for (int mb = 0; mb < 4; ++mb) {
            #pragma unroll
            for (int r = 0; r < 4; ++r) {
                int row = row0 + wm * 64 + mb * 16 + g * 4 + r;
                float v = acc[mb][nb][r] + bv;
                float u2 = 1.5957691216f * v + 0.0713548162f * (v * v * v);
                float e = exp2f(u2 * LOG2E_);
                float rr = __builtin_amdgcn_rcpf(e + 1.0f);
                float gl = v - v * rr;
                Hout[(size_t)row * 1024 + col] = bf16b(gl);
            }
        }
    }
}

// ---------------------------------------------------------------------------
// GEMM2: X[16384,256] += A[16384,1024]_bf16 @ W^T[256,1024] + b2
// 128(M)x64(N) tile, 4 waves, K=1024. grid (4, 128).
// ---------------------------------------------------------------------------
__global__ __launch_bounds__(256) void gemm2_kernel(
    const ushort* __restrict__ A, const ushort* __restrict__ Bt,
    const float* __restrict__ bias, float* __restrict__ X)
{
    __shared__ ushort As[128 * 32];
    __shared__ ushort Bs[64 * 32];
    const int tid = threadIdx.x;
    const int w = tid >> 6, l = tid & 63, g = l >> 4, ll = l & 15;
    const int row0 = blockIdx.y * 128, col0 = blockIdx.x * 64;

    const int srow = w * 32 + (l >> 2);
    const int scol = (l & 3) * 8;
    const ushort* ga = A  + (size_t)(row0 + srow) * 1024 + scol;
    const ushort* gb = Bt + (size_t)(col0 + w * 16 + (l >> 2)) * 1024 + scol;
    ushort* lA = &As[w * 1024 + l * 8];
    ushort* lB = &Bs[w * 512 + l * 8];

    f32x4 acc[2][4] = {};
    for (int k0 = 0; k0 < 1024; k0 += 32) {
        __syncthreads();
        gload16(ga + k0,             lA);
        gload16(ga + k0 + 16 * 1024, lA + 512);
        gload16(gb + k0,             lB);
        __syncthreads();
        frag af[2], bfr[4];
        #pragma unroll
        for (int mb = 0; mb < 2; ++mb)
            af[mb] = *(const frag*)&As[(w * 32 + mb * 16 + ll) * 32 + g * 8];
        #pragma unroll
        for (int nb = 0; nb < 4; ++nb)
            bfr[nb] = *(const frag*)&Bs[(nb * 16 + ll) * 32 + g * 8];
        #pragma unroll
        for (int mb = 0; mb < 2; ++mb)
            #pragma unroll
            for (int nb = 0; nb < 4; ++nb)
                acc[mb][nb] = MFMA(af[mb], bfr[nb], acc[mb][nb]);
    }

    #pragma unroll
    for (int nb = 0; nb < 4; ++nb) {
        int col = col0 + nb * 16 + ll;
        float bv = bias[col];
        #pragma unroll
        for (int mb = 0; mb < 2; ++mb) {
            #pragma unroll
            for (int r = 0; r < 4; ++r) {
                int row = row0 + w * 32 + mb * 16 + g * 4 + r;
                float* xp = X + (size_t)row * 256 + col;
                *xp += acc[mb][nb][r] + bv;
            }
        }
    }
}

// ---------------------------------------------------------------------------
extern "C" void kernel_launch(void* const* d_in, const int* in_sizes, int n_in,
                              void* d_out, int out_size, void* d_ws, size_t ws_size,
                              hipStream_t stream)
{
    const int*   tokens  = (const int*)d_in[0];
    const int*   pos_ids = (const int*)d_in[1];
    const float* emb     = (const float*)d_in[2];
    const float* iw      = (const float*)d_in[3];
    const float* pw      = (const float*)d_in[4];
    const float* ln1w    = (const float*)d_in[5];
    const float* ln1b    = (const float*)d_in[6];
    const float* ln2w    = (const float*)d_in[7];
    const float* ln2b    = (const float*)d_in[8];
    const float* w1      = (const float*)d_in[9];
    const float* b1      = (const float*)d_in[10];
    const float* w2      = (const float*)d_in[11];
    const float* b2      = (const float*)d_in[12];
    const float* lnfw    = (const float*)d_in[13];
    const float* lnfb    = (const float*)d_in[14];

    float* x = (float*)d_out;                    // [B,S,D] f32 residual stream
    char* ws = (char*)d_ws;
    ushort* xn   = (ushort*)ws;                  // 8,388,608 B
    ushort* vti  = (ushort*)(ws + 8388608);      // 8,388,608 B
    ushort* hbuf = (ushort*)(ws + 16777216);     // 33,554,432 B
    ushort* w1t  = (ushort*)(ws + 50331648);     // 3,145,728 B  [L][1024][256]
    ushort* w2t  = (ushort*)(ws + 53477376);     // 3,145,728 B  [L][256][1024]

    wtr_kernel<<<dim3(32, 8, L_), 256, 0, stream>>>(w1, w1t, 256, 1024);
    wtr_kernel<<<dim3(8, 32, L_), 256, 0, stream>>>(w2, w2t, 1024, 256);

    embed_kernel<<<B_ * S_, 256, 0, stream>>>(tokens, pos_ids, emb, iw, pw, x);

    for (int l = 0; l < L_; l++) {
        ln_kernel<1><<<(B_ * S_) / 4, 256, 0, stream>>>(x, ln1w + l * D_, ln1b + l * D_, xn);
        vtr_kernel<<<dim3(S_ / 128, B_ * H_), 256, 0, stream>>>(xn, vti);
        attn_kernel<<<(S_ / 64) * B_ * H_, 256, 0, stream>>>(xn, vti, x);
        ln_kernel<2><<<(B_ * S_) / 4, 256, 0, stream>>>(x, ln2w + l * D_, ln2b + l * D_, xn);
        gemm1_kernel<<<dim3(H2_ / 128, (B_ * S_) / 128), 256, 0, stream>>>(
            xn, w1t + (size_t)l * D_ * H2_, b1 + (size_t)l * H2_, hbuf);
        gemm2_kernel<<<dim3(D_ / 64, (B_ * S_) / 128), 256, 0, stream>>>(
            hbuf, w2t + (size_t)l * H2_ * D_, b2 + (size_t)l * D_, x);
    }
    ln_kernel<0><<<(B_ * S_) / 4, 256, 0, stream>>>(x, lnfw, lnfb, x);
}

// Round 6
// 754.257 us; speedup vs baseline: 5.9798x; 1.2855x over previous
//
#include <hip/hip_runtime.h>
#include <hip/hip_bf16.h>
#include <math.h>

#define B_   16
#define S_   1024
#define D_   256
#define H_   8
#define HD_  32
#define L_   6
#define H2_  1024
#define LN_EPS 1e-5f
#define LOG2E_ 1.4426950408889634f
#define SCALE_ 0.17677669529663687f  // 1/sqrt(32)

typedef __attribute__((ext_vector_type(8))) short frag;    // 8 bf16 (4 VGPRs)
typedef __attribute__((ext_vector_type(4))) float f32x4;

#define MFMA(a, b, c) __builtin_amdgcn_mfma_f32_16x16x32_bf16((a), (b), (c), 0, 0, 0)

__device__ inline ushort bf16b(float f) {
    uint u = __builtin_bit_cast(uint, f);
    u += 0x7fff + ((u >> 16) & 1);       // RNE
    return (ushort)(u >> 16);
}
__device__ inline uint cvt_pk_bf16(float lo, float hi) {
    uint r;
    asm("v_cvt_pk_bf16_f32 %0, %1, %2" : "=v"(r) : "v"(lo), "v"(hi));
    return r;
}
// async global->LDS, 16B per lane (dest = wave-uniform base + lane*16)
__device__ __forceinline__ void gload16(const ushort* g, ushort* l) {
    __builtin_amdgcn_global_load_lds(
        (const __attribute__((address_space(1))) uint*)g,
        (__attribute__((address_space(3))) uint*)l, 16, 0, 0);
}

// ---------------------------------------------------------------------------
// Weight transpose + f32->bf16: in [K][N] f32 -> out [N][K] bf16 (per layer z)
// ---------------------------------------------------------------------------
__global__ __launch_bounds__(256) void wtr_kernel(
    const float* __restrict__ in, ushort* __restrict__ out, int K, int N)
{
    __shared__ ushort Ts[32][36];
    in  += (size_t)blockIdx.z * K * N;
    out += (size_t)blockIdx.z * K * N;
    int n0 = blockIdx.x * 32, k0 = blockIdx.y * 32;
    int r = threadIdx.x >> 3, c4 = (threadIdx.x & 7) * 4;
    float4 f = *(const float4*)(in + (size_t)(k0 + r) * N + n0 + c4);
    Ts[r][c4 + 0] = bf16b(f.x);
    Ts[r][c4 + 1] = bf16b(f.y);
    Ts[r][c4 + 2] = bf16b(f.z);
    Ts[r][c4 + 3] = bf16b(f.w);
    __syncthreads();
    ushort4 o = { Ts[c4 + 0][r], Ts[c4 + 1][r], Ts[c4 + 2][r], Ts[c4 + 3][r] };
    *(ushort4*)(out + (size_t)(n0 + r) * K + k0 + c4) = o;
}

// ---------------------------------------------------------------------------
// Embedding (f32 out)
// ---------------------------------------------------------------------------
__global__ __launch_bounds__(256) void embed_kernel(
    const int* __restrict__ tokens, const int* __restrict__ pos_ids,
    const float* __restrict__ emb, const float* __restrict__ iwp,
    const float* __restrict__ pwp, float* __restrict__ X)
{
    int bs = blockIdx.x;
    int s = bs & (S_ - 1);
    int d = threadIdx.x;
    int tok = tokens[bs];
    float p = (float)pos_ids[s];
    int j = (d < 128) ? d : (d - 128);
    float invf = exp2f(-(float)j * (13.287712379549449f / 128.0f));
    float ang = p * invf;
    float pe = (d < 128) ? sinf(ang) : cosf(ang);
    X[(size_t)bs * D_ + d] = iwp[0] * emb[tok * D_ + d] + pwp[0] * pe;
}

// ---------------------------------------------------------------------------
// LayerNorm: wave per row. MODE 0: f32 row-major. MODE 1: bf16 head-packed
// [B][H][S][32]. MODE 2: bf16 row-major [M][256].
// ---------------------------------------------------------------------------
template<int MODE>
__global__ __launch_bounds__(256) void ln_kernel(
    const float* __restrict__ X, const float* __restrict__ w,
    const float* __restrict__ b, void* __restrict__ outp)
{
    int row = blockIdx.x * 4 + (threadIdx.x >> 6);
    int lane = threadIdx.x & 63;
    const float4 v = *(const float4*)(X + (size_t)row * D_ + lane * 4);
    float s = v.x + v.y + v.z + v.w;
    #pragma unroll
    for (int m = 1; m < 64; m <<= 1) s += __shfl_xor(s, m, 64);
    float mu = s * (1.0f / 256.0f);
    float dx = v.x - mu, dy = v.y - mu, dz = v.z - mu, dw = v.w - mu;
    float vs = dx * dx + dy * dy + dz * dz + dw * dw;
    #pragma unroll
    for (int m = 1; m < 64; m <<= 1) vs += __shfl_xor(vs, m, 64);
    float inv = rsqrtf(vs * (1.0f / 256.0f) + LN_EPS);
    float4 wv = *(const float4*)(w + lane * 4);
    float4 bv = *(const float4*)(b + lane * 4);
    float o0 = dx * inv * wv.x + bv.x;
    float o1 = dy * inv * wv.y + bv.y;
    float o2 = dz * inv * wv.z + bv.z;
    float o3 = dw * inv * wv.w + bv.w;
    if constexpr (MODE == 0) {
        float4 o = { o0, o1, o2, o3 };
        *(float4*)((float*)outp + (size_t)row * D_ + lane * 4) = o;
    } else if constexpr (MODE == 1) {
        int bb = row >> 10, ss = row & 1023;
        int h = lane >> 3, dd = (lane & 7) * 4;
        ushort4 o = { bf16b(o0), bf16b(o1), bf16b(o2), bf16b(o3) };
        *(ushort4*)((ushort*)outp + (((size_t)(bb * H_ + h) * S_ + ss) * HD_ + dd)) = o;
    } else {
        ushort4 o = { bf16b(o0), bf16b(o1), bf16b(o2), bf16b(o3) };
        *(ushort4*)((ushort*)outp + (size_t)row * D_ + lane * 4) = o;
    }
}

// ---------------------------------------------------------------------------
// V transpose: XNB [bh][s][32] -> VTI [bh][d][s'] with per-64-block key
// permutation sigma(t) = 32*(j&1) + 8*g + 4*(j>>1) + r, t = 16j + 4g + r.
// This makes exp2'd swapped-QK scores directly the PV A-fragment.
// ---------------------------------------------------------------------------
__global__ __launch_bounds__(256) void vtr_kernel(
    const ushort* __restrict__ XNB, ushort* __restrict__ VTI)
{
    __shared__ ushort Ts[32][136];
    const int bh = blockIdx.y;
    const int sblk = blockIdx.x * 128;
    const ushort* __restrict__ base = XNB + (size_t)bh * (S_ * HD_);
    #pragma unroll
    for (int i = 0; i < 2; ++i) {
        int cid = i * 256 + threadIdx.x;
        int s = cid >> 2, c = cid & 3;
        uint4 u = *(const uint4*)(base + (size_t)(sblk + s) * HD_ + c * 8);
        int col = (s & ~63) + 32 * ((s >> 4) & 1) + 8 * ((s >> 2) & 3)
                + 4 * ((s >> 5) & 1) + (s & 3);
        int d0 = c * 8;
        Ts[d0 + 0][col] = (ushort)(u.x & 0xffff);
        Ts[d0 + 1][col] = (ushort)(u.x >> 16);
        Ts[d0 + 2][col] = (ushort)(u.y & 0xffff);
        Ts[d0 + 3][col] = (ushort)(u.y >> 16);
        Ts[d0 + 4][col] = (ushort)(u.z & 0xffff);
        Ts[d0 + 5][col] = (ushort)(u.z >> 16);
        Ts[d0 + 6][col] = (ushort)(u.w & 0xffff);
        Ts[d0 + 7][col] = (ushort)(u.w >> 16);
    }
    __syncthreads();
    #pragma unroll
    for (int i = 0; i < 2; ++i) {
        int cid = i * 256 + threadIdx.x;
        int d = cid >> 4, ch = cid & 15;
        uint4 o = *(const uint4*)&Ts[d][ch * 8];
        *(uint4*)(VTI + ((size_t)bh * HD_ + d) * S_ + sblk + ch * 8) = o;
    }
}

// ---------------------------------------------------------------------------
// Flash attention v3: 32 q-rows/wave (2 Q frags), 64-key rounds, swapped QK^T,
// zero LDS / zero cross-lane, no-max softmax. 8 loads feed 20 MFMAs per round
// (2x the MFMA:load ratio of v2); K AND V prefetched one full round ahead.
// Block = 128 q-rows. grid = 1024, XCD-remapped so a bh stays on one XCD.
// ---------------------------------------------------------------------------
__global__ __launch_bounds__(256) void attn_kernel(
    const ushort* __restrict__ XNB, const ushort* __restrict__ VTI,
    float* __restrict__ X)
{
    const int bi = blockIdx.x;
    const int xcd = bi & 7, m = bi >> 3;          // m in [0,128)
    const int bh = xcd * 16 + (m >> 3);           // 16 bh per XCD
    const int bx = m & 7;                         // q-block (of 128) within bh
    const int b = bh >> 3, h = bh & 7;

    const ushort* __restrict__ base = XNB + (size_t)bh * (S_ * HD_);
    const ushort* __restrict__ vbase = VTI + (size_t)bh * (HD_ * S_);
    const int tid = threadIdx.x;
    const int w = tid >> 6, l = tid & 63, g = l >> 4, ll = l & 15;
    const int q0 = bx * 128 + w * 32;
    const int qgA = q0 + ll, qgB = q0 + 16 + ll;
    const int xq = q0 >> 5;                       // wave-constant (q0 % 32 == 0)

    const float C1 = SCALE_ * LOG2E_;
    frag qfA = *(const frag*)(base + (size_t)qgA * HD_ + g * 8);
    frag qfB = *(const frag*)(base + (size_t)qgB * HD_ + g * 8);
    #pragma unroll
    for (int i = 0; i < 8; ++i) {
        float fa = __builtin_bit_cast(float, ((uint)(ushort)qfA[i]) << 16);
        float fb = __builtin_bit_cast(float, ((uint)(ushort)qfB[i]) << 16);
        qfA[i] = (short)bf16b(fa * C1);
        qfB[i] = (short)bf16b(fb * C1);
    }

    const float slr = -exp2f(-(0.5f + (float)h)) * LOG2E_;
    const float sll = -exp2f(-(1.0f + (float)h)) * LOG2E_;
    const int itb = 2 * bx + (w >> 1);            // this wave's single boundary round

    // delta = ll - (4g + r); dyA0=|d|, dyA1=16-d, dyB0=16+d, dyB1=|d|
    float dabs[4], d16m[4], d16p[4];
    #pragma unroll
    for (int r = 0; r < 4; ++r) {
        int del = ll - 4 * g - r;
        dabs[r] = (float)abs(del);
        d16m[r] = (float)(16 - del);
        d16p[r] = (float)(16 + del);
    }

    f32x4 o0A = {0,0,0,0}, o1A = {0,0,0,0}, osA = {0,0,0,0};
    f32x4 o0B = {0,0,0,0}, o1B = {0,0,0,0}, osB = {0,0,0,0};
    const f32x4 zc = {0,0,0,0};
    const short one_s = (short)0x3F80;
    const frag ones = { one_s, one_s, one_s, one_s, one_s, one_s, one_s, one_s };

    frag kf0 = *(const frag*)(base + (size_t)(ll)      * HD_ + g * 8);
    frag kf1 = *(const frag*)(base + (size_t)(16 + ll) * HD_ + g * 8);
    frag kf2 = *(const frag*)(base + (size_t)(32 + ll) * HD_ + g * 8);
    frag kf3 = *(const frag*)(base + (size_t)(48 + ll) * HD_ + g * 8);
    frag vf0 = *(const frag*)(vbase + (size_t)(ll)      * S_ + g * 8);
    frag vf1 = *(const frag*)(vbase + (size_t)(16 + ll) * S_ + g * 8);
    frag vf2 = *(const frag*)(vbase + (size_t)(ll)      * S_ + 32 + g * 8);
    frag vf3 = *(const frag*)(vbase + (size_t)(16 + ll) * S_ + 32 + g * 8);

    for (int it = 0; it < 16; ++it) {
        const int tb = it * 64;
        const int nt = (it < 15) ? tb + 64 : tb;   // redundant last-round prefetch
        frag nk0 = *(const frag*)(base + (size_t)(nt + ll)      * HD_ + g * 8);
        frag nk1 = *(const frag*)(base + (size_t)(nt + 16 + ll) * HD_ + g * 8);
        frag nk2 = *(const frag*)(base + (size_t)(nt + 32 + ll) * HD_ + g * 8);
        frag nk3 = *(const frag*)(base + (size_t)(nt + 48 + ll) * HD_ + g * 8);
        frag nv0 = *(const frag*)(vbase + (size_t)(ll)      * S_ + nt + g * 8);
        frag nv1 = *(const frag*)(vbase + (size_t)(16 + ll) * S_ + nt + g * 8);
        frag nv2 = *(const frag*)(vbase + (size_t)(ll)      * S_ + nt + 32 + g * 8);
        frag nv3 = *(const frag*)(vbase + (size_t)(16 + ll) * S_ + nt + 32 + g * 8);

        __builtin_amdgcn_s_setprio(1);
        f32x4 sa0 = MFMA(kf0, qfA, zc);
        f32x4 sa1 = MFMA(kf1, qfA, zc);
        f32x4 sa2 = MFMA(kf2, qfA, zc);
        f32x4 sa3 = MFMA(kf3, qfA, zc);
        f32x4 sb0 = MFMA(kf0, qfB, zc);
        f32x4 sb1 = MFMA(kf1, qfB, zc);
        f32x4 sb2 = MFMA(kf2, qfB, zc);
        f32x4 sb3 = MFMA(kf3, qfB, zc);
        __builtin_amdgcn_s_setprio(0);

        float eA0[4], eA1[4], eA2[4], eA3[4];
        float eB0[4], eB1[4], eB2[4], eB3[4];
        if (it == itb) {
            // boundary round: exact per-score slope + distance
            #pragma unroll
            for (int r = 0; r < 4; ++r) {
                #pragma unroll
                for (int j = 0; j < 4; ++j) {
                    int tg = tb + 16 * j + 4 * g + r;
                    int xt = tg >> 5, yt = tg & 31;
                    float dA = (float)(abs(xq - xt) + abs((qgA & 31) - yt));
                    float dB = (float)(abs(xq - xt) + abs((qgB & 31) - yt));
                    float slA = (tg > qgA) ? slr : sll;
                    float slB = (tg > qgB) ? slr : sll;
                    float vA = fmaf(slA, dA, (j == 0 ? sa0[r] : j == 1 ? sa1[r] : j == 2 ? sa2[r] : sa3[r]));
                    float vB = fmaf(slB, dB, (j == 0 ? sb0[r] : j == 1 ? sb1[r] : j == 2 ? sb2[r] : sb3[r]));
                    float* eA = (j == 0 ? eA0 : j == 1 ? eA1 : j == 2 ? eA2 : eA3);
                    float* eB = (j == 0 ? eB0 : j == 1 ? eB1 : j == 2 ? eB2 : eB3);
                    eA[r] = exp2f(vA);
                    eB[r] = exp2f(vB);
                }
            }
        } else {
            const float sl = (it > itb) ? slr : sll;
            const float ax0 = (float)abs(xq - 2 * it);
            const float ax1 = (float)abs(xq - 2 * it - 1);
            #pragma unroll
            for (int r = 0; r < 4; ++r) {
                eA0[r] = exp2f(fmaf(sl, dabs[r] + ax0, sa0[r]));
                eA1[r] = exp2f(fmaf(sl, d16m[r] + ax0, sa1[r]));
                eA2[r] = exp2f(fmaf(sl, dabs[r] + ax1, sa2[r]));
                eA3[r] = exp2f(fmaf(sl, d16m[r] + ax1, sa3[r]));
                eB0[r] = exp2f(fmaf(sl, d16p[r] + ax0, sb0[r]));
                eB1[r] = exp2f(fmaf(sl, dabs[r] + ax0, sb1[r]));
                eB2[r] = exp2f(fmaf(sl, d16p[r] + ax1, sb2[r]));
                eB3[r] = exp2f(fmaf(sl, dabs[r] + ax1, sb3[r]));
            }
        }
        uint4 pa0 = { cvt_pk_bf16(eA0[0], eA0[1]), cvt_pk_bf16(eA0[2], eA0[3]),
                      cvt_pk_bf16(eA2[0], eA2[1]), cvt_pk_bf16(eA2[2], eA2[3]) };
        uint4 pa1 = { cvt_pk_bf16(eA1[0], eA1[1]), cvt_pk_bf16(eA1[2], eA1[3]),
                      cvt_pk_bf16(eA3[0], eA3[1]), cvt_pk_bf16(eA3[2], eA3[3]) };
        uint4 pb0 = { cvt_pk_bf16(eB0[0], eB0[1]), cvt_pk_bf16(eB0[2], eB0[3]),
                      cvt_pk_bf16(eB2[0], eB2[1]), cvt_pk_bf16(eB2[2], eB2[3]) };
        uint4 pb1 = { cvt_pk_bf16(eB1[0], eB1[1]), cvt_pk_bf16(eB1[2], eB1[3]),
                      cvt_pk_bf16(eB3[0], eB3[1]), cvt_pk_bf16(eB3[2], eB3[3]) };
        frag pfA0 = __builtin_bit_cast(frag, pa0);
        frag pfA1 = __builtin_bit_cast(frag, pa1);
        frag pfB0 = __builtin_bit_cast(frag, pb0);
        frag pfB1 = __builtin_bit_cast(frag, pb1);

        __builtin_amdgcn_s_setprio(1);
        o0A = MFMA(pfA0, vf0, o0A);
        o1A = MFMA(pfA0, vf1, o1A);
        osA = MFMA(pfA0, ones, osA);
        o0A = MFMA(pfA1, vf2, o0A);
        o1A = MFMA(pfA1, vf3, o1A);
        osA = MFMA(pfA1, ones, osA);
        o0B = MFMA(pfB0, vf0, o0B);
        o1B = MFMA(pfB0, vf1, o1B);
        osB = MFMA(pfB0, ones, osB);
        o0B = MFMA(pfB1, vf2, o0B);
        o1B = MFMA(pfB1, vf3, o1B);
        osB = MFMA(pfB1, ones, osB);
        __builtin_amdgcn_s_setprio(0);

        kf0 = nk0; kf1 = nk1; kf2 = nk2; kf3 = nk3;
        vf0 = nv0; vf1 = nv1; vf2 = nv2; vf3 = nv3;
    }

    #pragma unroll
    for (int r = 0; r < 4; ++r) {
        float invA = 1.0f / osA[r];
        float invB = 1.0f / osB[r];
        float* xpA = X + ((size_t)(b * S_ + q0 + g * 4 + r)) * D_ + h * HD_;
        float* xpB = X + ((size_t)(b * S_ + q0 + 16 + g * 4 + r)) * D_ + h * HD_;
        xpA[ll]      += o0A[r] * invA;
        xpA[16 + ll] += o1A[r] * invA;
        xpB[ll]      += o0B[r] * invB;
        xpB[16 + ll] += o1B[r] * invB;
    }
}

// ---------------------------------------------------------------------------
// GEMM1: H[16384,1024] = GELU(A[16384,256]_bf16 @ W^T[1024,256] + b1), bf16 out
// m97 structure: global_load_lds dwordx4 -> linear [128][32] LDS, 2 barriers.
// ---------------------------------------------------------------------------
__global__ __launch_bounds__(256) void gemm1_kernel(
    const ushort* __restrict__ A, const ushort* __restrict__ Bt,
    const float* __restrict__ bias, ushort* __restrict__ Hout)
{
    __shared__ ushort As[128 * 32];
    __shared__ ushort Bs[128 * 32];
    const int tid = threadIdx.x;
    const int w = tid >> 6, l = tid & 63, g = l >> 4, ll = l & 15;
    const int wm = w >> 1, wn = w & 1;
    const int row0 = blockIdx.y * 128, col0 = blockIdx.x * 128;

    const int srow = w * 32 + (l >> 2);
    const int scol = (l & 3) * 8;
    const ushort* ga = A  + (size_t)(row0 + srow) * 256 + scol;
    const ushort* gb = Bt + (size_t)(col0 + srow) * 256 + scol;
    ushort* lA = &As[w * 1024 + l * 8];
    ushort* lB = &Bs[w * 1024 + l * 8];

    f32x4 acc[4][4] = {};
    for (int k0 = 0; k0 < 256; k0 += 32) {
        __syncthreads();
        gload16(ga + k0,            lA);
        gload16(ga + k0 + 16 * 256, lA + 512);
        gload16(gb + k0,            lB);
        gload16(gb + k0 + 16 * 256, lB + 512);
        __syncthreads();
        frag af[4], bfr[4];
        #pragma unroll
        for (int mb = 0; mb < 4; ++mb)
            af[mb] = *(const frag*)&As[(wm * 64 + mb * 16 + ll) * 32 + g * 8];
        #pragma unroll
        for (int nb = 0; nb < 4; ++nb)
            bfr[nb] = *(const frag*)&Bs[(wn * 64 + nb * 16 + ll) * 32 + g * 8];
        #pragma unroll
        for (int mb = 0; mb < 4; ++mb)
            #pragma unroll
            for (int nb = 0; nb < 4; ++nb)
                acc[mb][nb] = MFMA(af[mb], bfr[nb], acc[mb][nb]);
    }

    #pragma unroll
    for (int nb = 0; nb < 4; ++nb) {
        int col = col0 + wn * 64 + nb * 16 + ll;
        float bv = bias[col];
        #pragma unroll
        for (int mb = 0; mb < 4; ++mb) {
            #pragma unroll
            for (int r = 0; r < 4; ++r) {
                int row = row0 + wm * 64 + mb * 16 + g * 4 + r;
                float v = acc[mb][nb][r] + bv;
                float u2 = 1.5957691216f * v + 0.0713548162f * (v * v * v);
                float e = exp2f(u2 * LOG2E_);
                float rr = __builtin_amdgcn_rcpf(e + 1.0f);
                float gl = v - v * rr;
                Hout[(size_t)row * 1024 + col] = bf16b(gl);
            }
        }
    }
}

// ---------------------------------------------------------------------------
// GEMM2: X[16384,256] += A[16384,1024]_bf16 @ W^T[256,1024] + b2
// 128(M)x64(N) tile, 4 waves, K=1024. grid (4, 128).
// ---------------------------------------------------------------------------
__global__ __launch_bounds__(256) void gemm2_kernel(
    const ushort* __restrict__ A, const ushort* __restrict__ Bt,
    const float* __restrict__ bias, float* __restrict__ X)
{
    __shared__ ushort As[128 * 32];
    __shared__ ushort Bs[64 * 32];
    const int tid = threadIdx.x;
    const int w = tid >> 6, l = tid & 63, g = l >> 4, ll = l & 15;
    const int row0 = blockIdx.y * 128, col0 = blockIdx.x * 64;

    const int srow = w * 32 + (l >> 2);
    const int scol = (l & 3) * 8;
    const ushort* ga = A  + (size_t)(row0 + srow) * 1024 + scol;
    const ushort* gb = Bt + (size_t)(col0 + w * 16 + (l >> 2)) * 1024 + scol;
    ushort* lA = &As[w * 1024 + l * 8];
    ushort* lB = &Bs[w * 512 + l * 8];

    f32x4 acc[2][4] = {};
    for (int k0 = 0; k0 < 1024; k0 += 32) {
        __syncthreads();
        gload16(ga + k0,             lA);
        gload16(ga + k0 + 16 * 1024, lA + 512);
        gload16(gb + k0,             lB);
        __syncthreads();
        frag af[2], bfr[4];
        #pragma unroll
        for (int mb = 0; mb < 2; ++mb)
            af[mb] = *(const frag*)&As[(w * 32 + mb * 16 + ll) * 32 + g * 8];
        #pragma unroll
        for (int nb = 0; nb < 4; ++nb)
            bfr[nb] = *(const frag*)&Bs[(nb * 16 + ll) * 32 + g * 8];
        #pragma unroll
        for (int mb = 0; mb < 2; ++mb)
            #pragma unroll
            for (int nb = 0; nb < 4; ++nb)
                acc[mb][nb] = MFMA(af[mb], bfr[nb], acc[mb][nb]);
    }

    #pragma unroll
    for (int nb = 0; nb < 4; ++nb) {
        int col = col0 + nb * 16 + ll;
        float bv = bias[col];
        #pragma unroll
        for (int mb = 0; mb < 2; ++mb) {
            #pragma unroll
            for (int r = 0; r < 4; ++r) {
                int row = row0 + w * 32 + mb * 16 + g * 4 + r;
                float* xp = X + (size_t)row * 256 + col;
                *xp += acc[mb][nb][r] + bv;
            }
        }
    }
}

// ---------------------------------------------------------------------------
extern "C" void kernel_launch(void* const* d_in, const int* in_sizes, int n_in,
                              void* d_out, int out_size, void* d_ws, size_t ws_size,
                              hipStream_t stream)
{
    const int*   tokens  = (const int*)d_in[0];
    const int*   pos_ids = (const int*)d_in[1];
    const float* emb     = (const float*)d_in[2];
    const float* iw      = (const float*)d_in[3];
    const float* pw      = (const float*)d_in[4];
    const float* ln1w    = (const float*)d_in[5];
    const float* ln1b    = (const float*)d_in[6];
    const float* ln2w    = (const float*)d_in[7];
    const float* ln2b    = (const float*)d_in[8];
    const float* w1      = (const float*)d_in[9];
    const float* b1      = (const float*)d_in[10];
    const float* w2      = (const float*)d_in[11];
    const float* b2      = (const float*)d_in[12];
    const float* lnfw    = (const float*)d_in[13];
    const float* lnfb    = (const float*)d_in[14];

    float* x = (float*)d_out;                    // [B,S,D] f32 residual stream
    char* ws = (char*)d_ws;
    ushort* xn   = (ushort*)ws;                  // 8,388,608 B
    ushort* vti  = (ushort*)(ws + 8388608);      // 8,388,608 B
    ushort* hbuf = (ushort*)(ws + 16777216);     // 33,554,432 B
    ushort* w1t  = (ushort*)(ws + 50331648);     // 3,145,728 B  [L][1024][256]
    ushort* w2t  = (ushort*)(ws + 53477376);     // 3,145,728 B  [L][256][1024]

    wtr_kernel<<<dim3(32, 8, L_), 256, 0, stream>>>(w1, w1t, 256, 1024);
    wtr_kernel<<<dim3(8, 32, L_), 256, 0, stream>>>(w2, w2t, 1024, 256);

    embed_kernel<<<B_ * S_, 256, 0, stream>>>(tokens, pos_ids, emb, iw, pw, x);

    for (int l = 0; l < L_; l++) {
        ln_kernel<1><<<(B_ * S_) / 4, 256, 0, stream>>>(x, ln1w + l * D_, ln1b + l * D_, xn);
        vtr_kernel<<<dim3(S_ / 128, B_ * H_), 256, 0, stream>>>(xn, vti);
        attn_kernel<<<(S_ / 128) * B_ * H_, 256, 0, stream>>>(xn, vti, x);
        ln_kernel<2><<<(B_ * S_) / 4, 256, 0, stream>>>(x, ln2w + l * D_, ln2b + l * D_, xn);
        gemm1_kernel<<<dim3(H2_ / 128, (B_ * S_) / 128), 256, 0, stream>>>(
            xn, w1t + (size_t)l * D_ * H2_, b1 + (size_t)l * H2_, hbuf);
        gemm2_kernel<<<dim3(D_ / 64, (B_ * S_) / 128), 256, 0, stream>>>(
            hbuf, w2t + (size_t)l * H2_ * D_, b2 + (size_t)l * D_, x);
    }
    ln_kernel<0><<<(B_ * S_) / 4, 256, 0, stream>>>(x, lnfw, lnfb, x);
}

// Round 7
// 730.601 us; speedup vs baseline: 6.1734x; 1.0324x over previous
//
#include <hip/hip_runtime.h>
#include <hip/hip_bf16.h>
#include <math.h>

#define B_   16
#define S_   1024
#define D_   256
#define H_   8
#define HD_  32
#define L_   6
#define H2_  1024
#define LN_EPS 1e-5f
#define LOG2E_ 1.4426950408889634f
#define SCALE_ 0.17677669529663687f  // 1/sqrt(32)

typedef __attribute__((ext_vector_type(8))) short frag;    // 8 bf16 (4 VGPRs)
typedef __attribute__((ext_vector_type(4))) float f32x4;

#define MFMA(a, b, c) __builtin_amdgcn_mfma_f32_16x16x32_bf16((a), (b), (c), 0, 0, 0)

__device__ inline ushort bf16b(float f) {
    uint u = __builtin_bit_cast(uint, f);
    u += 0x7fff + ((u >> 16) & 1);       // RNE
    return (ushort)(u >> 16);
}
__device__ inline uint cvt_pk_bf16(float lo, float hi) {
    uint r;
    asm("v_cvt_pk_bf16_f32 %0, %1, %2" : "=v"(r) : "v"(lo), "v"(hi));
    return r;
}
__device__ inline float exp2_raw(float x) {   // raw v_exp_f32 (2^x), no libm wrapper
    float r;
    asm("v_exp_f32 %0, %1" : "=v"(r) : "v"(x));
    return r;
}
// async global->LDS, 16B per lane (dest = wave-uniform base + lane*16)
__device__ __forceinline__ void gload16(const ushort* g, ushort* l) {
    __builtin_amdgcn_global_load_lds(
        (const __attribute__((address_space(1))) uint*)g,
        (__attribute__((address_space(3))) uint*)l, 16, 0, 0);
}

// ---------------------------------------------------------------------------
// Weight transpose + f32->bf16: in [K][N] f32 -> out [N][K] bf16 (per layer z)
// ---------------------------------------------------------------------------
__global__ __launch_bounds__(256) void wtr_kernel(
    const float* __restrict__ in, ushort* __restrict__ out, int K, int N)
{
    __shared__ ushort Ts[32][36];
    in  += (size_t)blockIdx.z * K * N;
    out += (size_t)blockIdx.z * K * N;
    int n0 = blockIdx.x * 32, k0 = blockIdx.y * 32;
    int r = threadIdx.x >> 3, c4 = (threadIdx.x & 7) * 4;
    float4 f = *(const float4*)(in + (size_t)(k0 + r) * N + n0 + c4);
    Ts[r][c4 + 0] = bf16b(f.x);
    Ts[r][c4 + 1] = bf16b(f.y);
    Ts[r][c4 + 2] = bf16b(f.z);
    Ts[r][c4 + 3] = bf16b(f.w);
    __syncthreads();
    ushort4 o = { Ts[c4 + 0][r], Ts[c4 + 1][r], Ts[c4 + 2][r], Ts[c4 + 3][r] };
    *(ushort4*)(out + (size_t)(n0 + r) * K + k0 + c4) = o;
}

// ---------------------------------------------------------------------------
// Embedding (f32 out)
// ---------------------------------------------------------------------------
__global__ __launch_bounds__(256) void embed_kernel(
    const int* __restrict__ tokens, const int* __restrict__ pos_ids,
    const float* __restrict__ emb, const float* __restrict__ iwp,
    const float* __restrict__ pwp, float* __restrict__ X)
{
    int bs = blockIdx.x;
    int s = bs & (S_ - 1);
    int d = threadIdx.x;
    int tok = tokens[bs];
    float p = (float)pos_ids[s];
    int j = (d < 128) ? d : (d - 128);
    float invf = exp2f(-(float)j * (13.287712379549449f / 128.0f));
    float ang = p * invf;
    float pe = (d < 128) ? sinf(ang) : cosf(ang);
    X[(size_t)bs * D_ + d] = iwp[0] * emb[tok * D_ + d] + pwp[0] * pe;
}

// ---------------------------------------------------------------------------
// LayerNorm: wave per row. MODE 0: f32 row-major. MODE 1: bf16 head-packed
// [B][H][S][32]. MODE 2: bf16 row-major [M][256].
// ---------------------------------------------------------------------------
template<int MODE>
__global__ __launch_bounds__(256) void ln_kernel(
    const float* __restrict__ X, const float* __restrict__ w,
    const float* __restrict__ b, void* __restrict__ outp)
{
    int row = blockIdx.x * 4 + (threadIdx.x >> 6);
    int lane = threadIdx.x & 63;
    const float4 v = *(const float4*)(X + (size_t)row * D_ + lane * 4);
    float s = v.x + v.y + v.z + v.w;
    #pragma unroll
    for (int m = 1; m < 64; m <<= 1) s += __shfl_xor(s, m, 64);
    float mu = s * (1.0f / 256.0f);
    float dx = v.x - mu, dy = v.y - mu, dz = v.z - mu, dw = v.w - mu;
    float vs = dx * dx + dy * dy + dz * dz + dw * dw;
    #pragma unroll
    for (int m = 1; m < 64; m <<= 1) vs += __shfl_xor(vs, m, 64);
    float inv = rsqrtf(vs * (1.0f / 256.0f) + LN_EPS);
    float4 wv = *(const float4*)(w + lane * 4);
    float4 bv = *(const float4*)(b + lane * 4);
    float o0 = dx * inv * wv.x + bv.x;
    float o1 = dy * inv * wv.y + bv.y;
    float o2 = dz * inv * wv.z + bv.z;
    float o3 = dw * inv * wv.w + bv.w;
    if constexpr (MODE == 0) {
        float4 o = { o0, o1, o2, o3 };
        *(float4*)((float*)outp + (size_t)row * D_ + lane * 4) = o;
    } else if constexpr (MODE == 1) {
        int bb = row >> 10, ss = row & 1023;
        int h = lane >> 3, dd = (lane & 7) * 4;
        ushort4 o = { bf16b(o0), bf16b(o1), bf16b(o2), bf16b(o3) };
        *(ushort4*)((ushort*)outp + (((size_t)(bb * H_ + h) * S_ + ss) * HD_ + dd)) = o;
    } else {
        ushort4 o = { bf16b(o0), bf16b(o1), bf16b(o2), bf16b(o3) };
        *(ushort4*)((ushort*)outp + (size_t)row * D_ + lane * 4) = o;
    }
}

// ---------------------------------------------------------------------------
// V transpose: XNB [bh][s][32] -> VTI [bh][d][s'] with per-64-block key
// permutation sigma(t) = 32*(j&1) + 8*g + 4*(j>>1) + r, t = 16j + 4g + r.
// This makes exp2'd swapped-QK scores directly the PV A-fragment.
// ---------------------------------------------------------------------------
__global__ __launch_bounds__(256) void vtr_kernel(
    const ushort* __restrict__ XNB, ushort* __restrict__ VTI)
{
    __shared__ ushort Ts[32][136];
    const int bh = blockIdx.y;
    const int sblk = blockIdx.x * 128;
    const ushort* __restrict__ base = XNB + (size_t)bh * (S_ * HD_);
    #pragma unroll
    for (int i = 0; i < 2; ++i) {
        int cid = i * 256 + threadIdx.x;
        int s = cid >> 2, c = cid & 3;
        uint4 u = *(const uint4*)(base + (size_t)(sblk + s) * HD_ + c * 8);
        int col = (s & ~63) + 32 * ((s >> 4) & 1) + 8 * ((s >> 2) & 3)
                + 4 * ((s >> 5) & 1) + (s & 3);
        int d0 = c * 8;
        Ts[d0 + 0][col] = (ushort)(u.x & 0xffff);
        Ts[d0 + 1][col] = (ushort)(u.x >> 16);
        Ts[d0 + 2][col] = (ushort)(u.y & 0xffff);
        Ts[d0 + 3][col] = (ushort)(u.y >> 16);
        Ts[d0 + 4][col] = (ushort)(u.z & 0xffff);
        Ts[d0 + 5][col] = (ushort)(u.z >> 16);
        Ts[d0 + 6][col] = (ushort)(u.w & 0xffff);
        Ts[d0 + 7][col] = (ushort)(u.w >> 16);
    }
    __syncthreads();
    #pragma unroll
    for (int i = 0; i < 2; ++i) {
        int cid = i * 256 + threadIdx.x;
        int d = cid >> 4, ch = cid & 15;
        uint4 o = *(const uint4*)&Ts[d][ch * 8];
        *(uint4*)(VTI + ((size_t)bh * HD_ + d) * S_ + sblk + ch * 8) = o;
    }
}

// ---------------------------------------------------------------------------
// Flash attention v4: as v3 (32 q/wave, swapped QK^T, zero LDS, no-max) but:
//  - fully static e-value names (no scratch; rule #20 fix)
//  - raw v_exp_f32
//  - 3 advancing per-lane pointers + imm-offset loads (no per-round addr calc)
//  - unroll-2 ping-pong frag sets (no rotation moves)
// ---------------------------------------------------------------------------
__global__ __launch_bounds__(256) void attn_kernel(
    const ushort* __restrict__ XNB, const ushort* __restrict__ VTI,
    float* __restrict__ X)
{
    const int bi = blockIdx.x;
    const int xcd = bi & 7, m = bi >> 3;          // m in [0,128)
    const int bh = xcd * 16 + (m >> 3);           // 16 bh per XCD
    const int bx = m & 7;                         // q-block (of 128) within bh
    const int b = bh >> 3, h = bh & 7;

    const ushort* __restrict__ base = XNB + (size_t)bh * (S_ * HD_);
    const ushort* __restrict__ vbase = VTI + (size_t)bh * (HD_ * S_);
    const int tid = threadIdx.x;
    const int w = tid >> 6, l = tid & 63, g = l >> 4, ll = l & 15;
    const int q0 = bx * 128 + w * 32;
    const int qgA = q0 + ll, qgB = q0 + 16 + ll;
    const int xq = q0 >> 5;                       // wave-constant
    const int yqA = ll, yqB = 16 + ll;

    const float C1 = SCALE_ * LOG2E_;
    frag qfA = *(const frag*)(base + (size_t)qgA * HD_ + g * 8);
    frag qfB = *(const frag*)(base + (size_t)qgB * HD_ + g * 8);
    #pragma unroll
    for (int i = 0; i < 8; ++i) {
        float fa = __builtin_bit_cast(float, ((uint)(ushort)qfA[i]) << 16);
        float fb = __builtin_bit_cast(float, ((uint)(ushort)qfB[i]) << 16);
        qfA[i] = (short)bf16b(fa * C1);
        qfB[i] = (short)bf16b(fb * C1);
    }

    const float slr = -exp2f(-(0.5f + (float)h)) * LOG2E_;
    const float sll = -exp2f(-(1.0f + (float)h)) * LOG2E_;
    const int itb = 2 * bx + (w >> 1);            // this wave's boundary round

    // delta = ll - (4g + r): dabs=|d|, d16m=16-d, d16p=16+d (round-constant)
    float dabs[4], d16m[4], d16p[4];
    #pragma unroll
    for (int r = 0; r < 4; ++r) {
        int del = ll - 4 * g - r;
        dabs[r] = (float)abs(del);
        d16m[r] = (float)(16 - del);
        d16p[r] = (float)(16 + del);
    }

    f32x4 o0A = {0,0,0,0}, o1A = {0,0,0,0}, osA = {0,0,0,0};
    f32x4 o0B = {0,0,0,0}, o1B = {0,0,0,0}, osB = {0,0,0,0};
    const f32x4 zc = {0,0,0,0};
    const short one_s = (short)0x3F80;
    const frag ones = { one_s, one_s, one_s, one_s, one_s, one_s, one_s, one_s };

    // advancing per-lane pointers; all loads use compile-time imm offsets
    const ushort* kp  = base  + (size_t)ll * HD_ + g * 8;
    const ushort* vpa = vbase + (size_t)ll * S_ + g * 8;
    const ushort* vpb = vbase + (size_t)(16 + ll) * S_ + g * 8;

    frag Ka0, Ka1, Ka2, Ka3, Va0, Va1, Va2, Va3;
    frag Kb0, Kb1, Kb2, Kb3, Vb0, Vb1, Vb2, Vb3;

    Ka0 = *(const frag*)(kp);
    Ka1 = *(const frag*)(kp + 16 * HD_);
    Ka2 = *(const frag*)(kp + 32 * HD_);
    Ka3 = *(const frag*)(kp + 48 * HD_);
    Va0 = *(const frag*)(vpa);
    Va1 = *(const frag*)(vpb);
    Va2 = *(const frag*)(vpa + 32);
    Va3 = *(const frag*)(vpb + 32);
    kp += 64 * HD_; vpa += 64; vpb += 64;

#define EXACTR(r)                                                             \
  { int t0 = tb + 4 * g + (r);                                                \
    { int tg = t0;      int xt = tg >> 5, yt = tg & 31;                       \
      eA0[r] = exp2_raw(fmaf((tg > qgA) ? slr : sll,                          \
               (float)(abs(xq - xt) + abs(yqA - yt)), sa0[r]));               \
      eB0[r] = exp2_raw(fmaf((tg > qgB) ? slr : sll,                          \
               (float)(abs(xq - xt) + abs(yqB - yt)), sb0[r])); }             \
    { int tg = t0 + 16; int xt = tg >> 5, yt = tg & 31;                       \
      eA1[r] = exp2_raw(fmaf((tg > qgA) ? slr : sll,                          \
               (float)(abs(xq - xt) + abs(yqA - yt)), sa1[r]));               \
      eB1[r] = exp2_raw(fmaf((tg > qgB) ? slr : sll,                          \
               (float)(abs(xq - xt) + abs(yqB - yt)), sb1[r])); }             \
    { int tg = t0 + 32; int xt = tg >> 5, yt = tg & 31;                       \
      eA2[r] = exp2_raw(fmaf((tg > qgA) ? slr : sll,                          \
               (float)(abs(xq - xt) + abs(yqA - yt)), sa2[r]));               \
      eB2[r] = exp2_raw(fmaf((tg > qgB) ? slr : sll,                          \
               (float)(abs(xq - xt) + abs(yqB - yt)), sb2[r])); }             \
    { int tg = t0 + 48; int xt = tg >> 5, yt = tg & 31;                       \
      eA3[r] = exp2_raw(fmaf((tg > qgA) ? slr : sll,                          \
               (float)(abs(xq - xt) + abs(yqA - yt)), sa3[r]));               \
      eB3[r] = exp2_raw(fmaf((tg > qgB) ? slr : sll,                          \
               (float)(abs(xq - xt) + abs(yqB - yt)), sb3[r])); } }

#define FASTR(r)                                                              \
    eA0[r] = exp2_raw(fmaf(sl, dabs[r] + ax0, sa0[r]));                       \
    eA1[r] = exp2_raw(fmaf(sl, d16m[r] + ax0, sa1[r]));                       \
    eA2[r] = exp2_raw(fmaf(sl, dabs[r] + ax1, sa2[r]));                       \
    eA3[r] = exp2_raw(fmaf(sl, d16m[r] + ax1, sa3[r]));                       \
    eB0[r] = exp2_raw(fmaf(sl, d16p[r] + ax0, sb0[r]));                       \
    eB1[r] = exp2_raw(fmaf(sl, dabs[r] + ax0, sb1[r]));                       \
    eB2[r] = exp2_raw(fmaf(sl, d16p[r] + ax1, sb2[r]));                       \
    eB3[r] = exp2_raw(fmaf(sl, dabs[r] + ax1, sb3[r]));

#define STEP(IT, K0,K1,K2,K3, V0,V1,V2,V3, NK0,NK1,NK2,NK3, NV0,NV1,NV2,NV3) \
  { NK0 = *(const frag*)(kp);                                                 \
    NK1 = *(const frag*)(kp + 16 * HD_);                                      \
    NK2 = *(const frag*)(kp + 32 * HD_);                                      \
    NK3 = *(const frag*)(kp + 48 * HD_);                                      \
    NV0 = *(const frag*)(vpa);                                                \
    NV1 = *(const frag*)(vpb);                                                \
    NV2 = *(const frag*)(vpa + 32);                                           \
    NV3 = *(const frag*)(vpb + 32);                                           \
    kp += 64 * HD_; vpa += 64; vpb += 64;                                     \
    const int tb = (IT) * 64;                                                 \
    __builtin_amdgcn_s_setprio(1);                                            \
    f32x4 sa0 = MFMA(K0, qfA, zc);                                            \
    f32x4 sa1 = MFMA(K1, qfA, zc);                                            \
    f32x4 sa2 = MFMA(K2, qfA, zc);                                            \
    f32x4 sa3 = MFMA(K3, qfA, zc);                                            \
    f32x4 sb0 = MFMA(K0, qfB, zc);                                            \
    f32x4 sb1 = MFMA(K1, qfB, zc);                                            \
    f32x4 sb2 = MFMA(K2, qfB, zc);                                            \
    f32x4 sb3 = MFMA(K3, qfB, zc);                                            \
    __builtin_amdgcn_s_setprio(0);                                            \
    f32x4 eA0, eA1, eA2, eA3, eB0, eB1, eB2, eB3;                             \
    if ((IT) == itb) {                                                        \
        EXACTR(0) EXACTR(1) EXACTR(2) EXACTR(3)                               \
    } else {                                                                  \
        const float sl = ((IT) > itb) ? slr : sll;                            \
        const float ax0 = (float)abs(xq - 2 * (IT));                          \
        const float ax1 = (float)abs(xq - 2 * (IT) - 1);                      \
        FASTR(0) FASTR(1) FASTR(2) FASTR(3)                                   \
    }                                                                         \
    uint4 pa0 = { cvt_pk_bf16(eA0[0], eA0[1]), cvt_pk_bf16(eA0[2], eA0[3]),   \
                  cvt_pk_bf16(eA2[0], eA2[1]), cvt_pk_bf16(eA2[2], eA2[3]) }; \
    uint4 pa1 = { cvt_pk_bf16(eA1[0], eA1[1]), cvt_pk_bf16(eA1[2], eA1[3]),   \
                  cvt_pk_bf16(eA3[0], eA3[1]), cvt_pk_bf16(eA3[2], eA3[3]) }; \
    uint4 pb0 = { cvt_pk_bf16(eB0[0], eB0[1]), cvt_pk_bf16(eB0[2], eB0[3]),   \
                  cvt_pk_bf16(eB2[0], eB2[1]), cvt_pk_bf16(eB2[2], eB2[3]) }; \
    uint4 pb1 = { cvt_pk_bf16(eB1[0], eB1[1]), cvt_pk_bf16(eB1[2], eB1[3]),   \
                  cvt_pk_bf16(eB3[0], eB3[1]), cvt_pk_bf16(eB3[2], eB3[3]) }; \
    frag pfA0 = __builtin_bit_cast(frag, pa0);                                \
    frag pfA1 = __builtin_bit_cast(frag, pa1);                                \
    frag pfB0 = __builtin_bit_cast(frag, pb0);                                \
    frag pfB1 = __builtin_bit_cast(frag, pb1);                                \
    __builtin_amdgcn_s_setprio(1);                                            \
    o0A = MFMA(pfA0, V0, o0A);  o1A = MFMA(pfA0, V1, o1A);                    \
    osA = MFMA(pfA0, ones, osA);                                              \
    o0A = MFMA(pfA1, V2, o0A);  o1A = MFMA(pfA1, V3, o1A);                    \
    osA = MFMA(pfA1, ones, osA);                                              \
    o0B = MFMA(pfB0, V0, o0B);  o1B = MFMA(pfB0, V1, o1B);                    \
    osB = MFMA(pfB0, ones, osB);                                              \
    o0B = MFMA(pfB1, V2, o0B);  o1B = MFMA(pfB1, V3, o1B);                    \
    osB = MFMA(pfB1, ones, osB);                                              \
    __builtin_amdgcn_s_setprio(0);                                            \
  }

    for (int it2 = 0; it2 < 16; it2 += 2) {
        STEP(it2,     Ka0,Ka1,Ka2,Ka3, Va0,Va1,Va2,Va3,
                      Kb0,Kb1,Kb2,Kb3, Vb0,Vb1,Vb2,Vb3)
        STEP(it2 + 1, Kb0,Kb1,Kb2,Kb3, Vb0,Vb1,Vb2,Vb3,
                      Ka0,Ka1,Ka2,Ka3, Va0,Va1,Va2,Va3)
    }
#undef STEP
#undef FASTR
#undef EXACTR

    #pragma unroll
    for (int r = 0; r < 4; ++r) {
        float invA = 1.0f / osA[r];
        float invB = 1.0f / osB[r];
        float* xpA = X + ((size_t)(b * S_ + q0 + g * 4 + r)) * D_ + h * HD_;
        float* xpB = X + ((size_t)(b * S_ + q0 + 16 + g * 4 + r)) * D_ + h * HD_;
        xpA[ll]      += o0A[r] * invA;
        xpA[16 + ll] += o1A[r] * invA;
        xpB[ll]      += o0B[r] * invB;
        xpB[16 + ll] += o1B[r] * invB;
    }
}

// ---------------------------------------------------------------------------
// GEMM1: H[16384,1024] = GELU(A[16384,256]_bf16 @ W^T[1024,256] + b1), bf16 out
// ---------------------------------------------------------------------------
__global__ __launch_bounds__(256) void gemm1_kernel(
    const ushort* __restrict__ A, const ushort* __restrict__ Bt,
    const float* __restrict__ bias, ushort* __restrict__ Hout)
{
    __shared__ ushort As[128 * 32];
    __shared__ ushort Bs[128 * 32];
    const int tid = threadIdx.x;
    const int w = tid >> 6, l = tid & 63, g = l >> 4, ll = l & 15;
    const int wm = w >> 1, wn = w & 1;
    const int row0 = blockIdx.y * 128, col0 = blockIdx.x * 128;

    const int srow = w * 32 + (l >> 2);
    const int scol = (l & 3) * 8;
    const ushort* ga = A  + (size_t)(row0 + srow) * 256 + scol;
    const ushort* gb = Bt + (size_t)(col0 + srow) * 256 + scol;
    ushort* lA = &As[w * 1024 + l * 8];
    ushort* lB = &Bs[w * 1024 + l * 8];

    f32x4 acc[4][4] = {};
    for (int k0 = 0; k0 < 256; k0 += 32) {
        __syncthreads();
        gload16(ga + k0,            lA);
        gload16(ga + k0 + 16 * 256, lA + 512);
        gload16(gb + k0,            lB);
        gload16(gb + k0 + 16 * 256, lB + 512);
        __syncthreads();
        frag af[4], bfr[4];
        #pragma unroll
        for (int mb = 0; mb < 4; ++mb)
            af[mb] = *(const frag*)&As[(wm * 64 + mb * 16 + ll) * 32 + g * 8];
        #pragma unroll
        for (int nb = 0; nb < 4; ++nb)
            bfr[nb] = *(const frag*)&Bs[(wn * 64 + nb * 16 + ll) * 32 + g * 8];
        #pragma unroll
        for (int mb = 0; mb < 4; ++mb)
            #pragma unroll
            for (int nb = 0; nb < 4; ++nb)
                acc[mb][nb] = MFMA(af[mb], bfr[nb], acc[mb][nb]);
    }

    #pragma unroll
    for (int nb = 0; nb < 4; ++nb) {
        int col = col0 + wn * 64 + nb * 16 + ll;
        float bv = bias[col];
        #pragma unroll
        for (int mb = 0; mb < 4; ++mb) {
            #pragma unroll
            for (int r = 0; r < 4; ++r) {
                int row = row0 + wm * 64 + mb * 16 + g * 4 + r;
                float v = acc[mb][nb][r] + bv;
                float u2 = 1.5957691216f * v + 0.0713548162f * (v * v * v);
                float e = exp2_raw(u2 * LOG2E_);
                float rr = __builtin_amdgcn_rcpf(e + 1.0f);
                float gl = v - v * rr;
                Hout[(size_t)row * 1024 + col] = bf16b(gl);
            }
        }
    }
}

// ---------------------------------------------------------------------------
// GEMM2: X[16384,256] += A[16384,1024]_bf16 @ W^T[256,1024] + b2
// 128(M)x64(N) tile, 4 waves, K=1024. grid (4, 128).
// ---------------------------------------------------------------------------
__global__ __launch_bounds__(256) void gemm2_kernel(
    const ushort* __restrict__ A, const ushort* __restrict__ Bt,
    const float* __restrict__ bias, float* __restrict__ X)
{
    __shared__ ushort As[128 * 32];
    __shared__ ushort Bs[64 * 32];
    const int tid = threadIdx.x;
    const int w = tid >> 6, l = tid & 63, g = l >> 4, ll = l & 15;
    const int row0 = blockIdx.y * 128, col0 = blockIdx.x * 64;

    const int srow = w * 32 + (l >> 2);
    const int scol = (l & 3) * 8;
    const ushort* ga = A  + (size_t)(row0 + srow) * 1024 + scol;
    const ushort* gb = Bt + (size_t)(col0 + w * 16 + (l >> 2)) * 1024 + scol;
    ushort* lA = &As[w * 1024 + l * 8];
    ushort* lB = &Bs[w * 512 + l * 8];

    f32x4 acc[2][4] = {};
    for (int k0 = 0; k0 < 1024; k0 += 32) {
        __syncthreads();
        gload16(ga + k0,             lA);
        gload16(ga + k0 + 16 * 1024, lA + 512);
        gload16(gb + k0,             lB);
        __syncthreads();
        frag af[2], bfr[4];
        #pragma unroll
        for (int mb = 0; mb < 2; ++mb)
            af[mb] = *(const frag*)&As[(w * 32 + mb * 16 + ll) * 32 + g * 8];
        #pragma unroll
        for (int nb = 0; nb < 4; ++nb)
            bfr[nb] = *(const frag*)&Bs[(nb * 16 + ll) * 32 + g * 8];
        #pragma unroll
        for (int mb = 0; mb < 2; ++mb)
            #pragma unroll
            for (int nb = 0; nb < 4; ++nb)
                acc[mb][nb] = MFMA(af[mb], bfr[nb], acc[mb][nb]);
    }

    #pragma unroll
    for (int nb = 0; nb < 4; ++nb) {
        int col = col0 + nb * 16 + ll;
        float bv = bias[col];
        #pragma unroll
        for (int mb = 0; mb < 2; ++mb) {
            #pragma unroll
            for (int r = 0; r < 4; ++r) {
                int row = row0 + w * 32 + mb * 16 + g * 4 + r;
                float* xp = X + (size_t)row * 256 + col;
                *xp += acc[mb][nb][r] + bv;
            }
        }
    }
}

// ---------------------------------------------------------------------------
extern "C" void kernel_launch(void* const* d_in, const int* in_sizes, int n_in,
                              void* d_out, int out_size, void* d_ws, size_t ws_size,
                              hipStream_t stream)
{
    const int*   tokens  = (const int*)d_in[0];
    const int*   pos_ids = (const int*)d_in[1];
    const float* emb     = (const float*)d_in[2];
    const float* iw      = (const float*)d_in[3];
    const float* pw      = (const float*)d_in[4];
    const float* ln1w    = (const float*)d_in[5];
    const float* ln1b    = (const float*)d_in[6];
    const float* ln2w    = (const float*)d_in[7];
    const float* ln2b    = (const float*)d_in[8];
    const float* w1      = (const float*)d_in[9];
    const float* b1      = (const float*)d_in[10];
    const float* w2      = (const float*)d_in[11];
    const float* b2      = (const float*)d_in[12];
    const float* lnfw    = (const float*)d_in[13];
    const float* lnfb    = (const float*)d_in[14];

    float* x = (float*)d_out;                    // [B,S,D] f32 residual stream
    char* ws = (char*)d_ws;
    ushort* xn   = (ushort*)ws;                  // 8,388,608 B
    ushort* vti  = (ushort*)(ws + 8388608);      // 8,388,608 B
    ushort* hbuf = (ushort*)(ws + 16777216);     // 33,554,432 B
    ushort* w1t  = (ushort*)(ws + 50331648);     // 3,145,728 B  [L][1024][256]
    ushort* w2t  = (ushort*)(ws + 53477376);     // 3,145,728 B  [L][256][1024]

    wtr_kernel<<<dim3(32, 8, L_), 256, 0, stream>>>(w1, w1t, 256, 1024);
    wtr_kernel<<<dim3(8, 32, L_), 256, 0, stream>>>(w2, w2t, 1024, 256);

    embed_kernel<<<B_ * S_, 256, 0, stream>>>(tokens, pos_ids, emb, iw, pw, x);

    for (int l = 0; l < L_; l++) {
        ln_kernel<1><<<(B_ * S_) / 4, 256, 0, stream>>>(x, ln1w + l * D_, ln1b + l * D_, xn);
        vtr_kernel<<<dim3(S_ / 128, B_ * H_), 256, 0, stream>>>(xn, vti);
        attn_kernel<<<(S_ / 128) * B_ * H_, 256, 0, stream>>>(xn, vti, x);
        ln_kernel<2><<<(B_ * S_) / 4, 256, 0, stream>>>(x, ln2w + l * D_, ln2b + l * D_, xn);
        gemm1_kernel<<<dim3(H2_ / 128, (B_ * S_) / 128), 256, 0, stream>>>(
            xn, w1t + (size_t)l * D_ * H2_, b1 + (size_t)l * H2_, hbuf);
        gemm2_kernel<<<dim3(D_ / 64, (B_ * S_) / 128), 256, 0, stream>>>(
            hbuf, w2t + (size_t)l * H2_ * D_, b2 + (size_t)l * D_, x);
    }
    ln_kernel<0><<<(B_ * S_) / 4, 256, 0, stream>>>(x, lnfw, lnfb, x);
}

// Round 8
// 679.292 us; speedup vs baseline: 6.6397x; 1.0755x over previous
//
#include <hip/hip_runtime.h>
#include <hip/hip_bf16.h>
#include <math.h>

#define B_   16
#define S_   1024
#define D_   256
#define H_   8
#define HD_  32
#define L_   6
#define H2_  1024
#define LN_EPS 1e-5f
#define LOG2E_ 1.4426950408889634f
#define SCALE_ 0.17677669529663687f  // 1/sqrt(32)

typedef __attribute__((ext_vector_type(8))) short frag;    // 8 bf16 (4 VGPRs)
typedef __attribute__((ext_vector_type(4))) float f32x4;

#define MFMA(a, b, c) __builtin_amdgcn_mfma_f32_16x16x32_bf16((a), (b), (c), 0, 0, 0)

__device__ inline ushort bf16b(float f) {
    uint u = __builtin_bit_cast(uint, f);
    u += 0x7fff + ((u >> 16) & 1);       // RNE
    return (ushort)(u >> 16);
}
__device__ inline uint cvt_pk_bf16(float lo, float hi) {
    uint r;
    asm("v_cvt_pk_bf16_f32 %0, %1, %2" : "=v"(r) : "v"(lo), "v"(hi));
    return r;
}
__device__ inline float exp2_raw(float x) {   // raw v_exp_f32 (2^x), no libm wrapper
    float r;
    asm("v_exp_f32 %0, %1" : "=v"(r) : "v"(x));
    return r;
}
// async global->LDS, 16B per lane (dest = wave-uniform base + lane*16)
__device__ __forceinline__ void gload16(const ushort* g, ushort* l) {
    __builtin_amdgcn_global_load_lds(
        (const __attribute__((address_space(1))) uint*)g,
        (__attribute__((address_space(3))) uint*)l, 16, 0, 0);
}

// ---------------------------------------------------------------------------
// Weight transpose + f32->bf16: in [K][N] f32 -> out [N][K] bf16 (per layer z)
// ---------------------------------------------------------------------------
__global__ __launch_bounds__(256) void wtr_kernel(
    const float* __restrict__ in, ushort* __restrict__ out, int K, int N)
{
    __shared__ ushort Ts[32][36];
    in  += (size_t)blockIdx.z * K * N;
    out += (size_t)blockIdx.z * K * N;
    int n0 = blockIdx.x * 32, k0 = blockIdx.y * 32;
    int r = threadIdx.x >> 3, c4 = (threadIdx.x & 7) * 4;
    float4 f = *(const float4*)(in + (size_t)(k0 + r) * N + n0 + c4);
    Ts[r][c4 + 0] = bf16b(f.x);
    Ts[r][c4 + 1] = bf16b(f.y);
    Ts[r][c4 + 2] = bf16b(f.z);
    Ts[r][c4 + 3] = bf16b(f.w);
    __syncthreads();
    ushort4 o = { Ts[c4 + 0][r], Ts[c4 + 1][r], Ts[c4 + 2][r], Ts[c4 + 3][r] };
    *(ushort4*)(out + (size_t)(n0 + r) * K + k0 + c4) = o;
}

// ---------------------------------------------------------------------------
// Embedding (f32 out)
// ---------------------------------------------------------------------------
__global__ __launch_bounds__(256) void embed_kernel(
    const int* __restrict__ tokens, const int* __restrict__ pos_ids,
    const float* __restrict__ emb, const float* __restrict__ iwp,
    const float* __restrict__ pwp, float* __restrict__ X)
{
    int bs = blockIdx.x;
    int s = bs & (S_ - 1);
    int d = threadIdx.x;
    int tok = tokens[bs];
    float p = (float)pos_ids[s];
    int j = (d < 128) ? d : (d - 128);
    float invf = exp2f(-(float)j * (13.287712379549449f / 128.0f));
    float ang = p * invf;
    float pe = (d < 128) ? sinf(ang) : cosf(ang);
    X[(size_t)bs * D_ + d] = iwp[0] * emb[tok * D_ + d] + pwp[0] * pe;
}

// ---------------------------------------------------------------------------
// LayerNorm: wave per row. MODE 0: f32 row-major. MODE 1: bf16 head-packed
// [B][H][S][32]. MODE 2: bf16 row-major [M][256].
// ---------------------------------------------------------------------------
template<int MODE>
__global__ __launch_bounds__(256) void ln_kernel(
    const float* __restrict__ X, const float* __restrict__ w,
    const float* __restrict__ b, void* __restrict__ outp)
{
    int row = blockIdx.x * 4 + (threadIdx.x >> 6);
    int lane = threadIdx.x & 63;
    const float4 v = *(const float4*)(X + (size_t)row * D_ + lane * 4);
    float s = v.x + v.y + v.z + v.w;
    #pragma unroll
    for (int m = 1; m < 64; m <<= 1) s += __shfl_xor(s, m, 64);
    float mu = s * (1.0f / 256.0f);
    float dx = v.x - mu, dy = v.y - mu, dz = v.z - mu, dw = v.w - mu;
    float vs = dx * dx + dy * dy + dz * dz + dw * dw;
    #pragma unroll
    for (int m = 1; m < 64; m <<= 1) vs += __shfl_xor(vs, m, 64);
    float inv = rsqrtf(vs * (1.0f / 256.0f) + LN_EPS);
    float4 wv = *(const float4*)(w + lane * 4);
    float4 bv = *(const float4*)(b + lane * 4);
    float o0 = dx * inv * wv.x + bv.x;
    float o1 = dy * inv * wv.y + bv.y;
    float o2 = dz * inv * wv.z + bv.z;
    float o3 = dw * inv * wv.w + bv.w;
    if constexpr (MODE == 0) {
        float4 o = { o0, o1, o2, o3 };
        *(float4*)((float*)outp + (size_t)row * D_ + lane * 4) = o;
    } else if constexpr (MODE == 1) {
        int bb = row >> 10, ss = row & 1023;
        int h = lane >> 3, dd = (lane & 7) * 4;
        ushort4 o = { bf16b(o0), bf16b(o1), bf16b(o2), bf16b(o3) };
        *(ushort4*)((ushort*)outp + (((size_t)(bb * H_ + h) * S_ + ss) * HD_ + dd)) = o;
    } else {
        ushort4 o = { bf16b(o0), bf16b(o1), bf16b(o2), bf16b(o3) };
        *(ushort4*)((ushort*)outp + (size_t)row * D_ + lane * 4) = o;
    }
}

// ---------------------------------------------------------------------------
// V transpose: XNB [bh][s][32] -> VTI [bh][d][s'] with per-64-block key
// permutation sigma(t) = 32*(j&1) + 8*g + 4*(j>>1) + r, t = 16j + 4g + r.
// This makes exp2'd swapped-QK scores directly the PV A-fragment.
// ---------------------------------------------------------------------------
__global__ __launch_bounds__(256) void vtr_kernel(
    const ushort* __restrict__ XNB, ushort* __restrict__ VTI)
{
    __shared__ ushort Ts[32][136];
    const int bh = blockIdx.y;
    const int sblk = blockIdx.x * 128;
    const ushort* __restrict__ base = XNB + (size_t)bh * (S_ * HD_);
    #pragma unroll
    for (int i = 0; i < 2; ++i) {
        int cid = i * 256 + threadIdx.x;
        int s = cid >> 2, c = cid & 3;
        uint4 u = *(const uint4*)(base + (size_t)(sblk + s) * HD_ + c * 8);
        int col = (s & ~63) + 32 * ((s >> 4) & 1) + 8 * ((s >> 2) & 3)
                + 4 * ((s >> 5) & 1) + (s & 3);
        int d0 = c * 8;
        Ts[d0 + 0][col] = (ushort)(u.x & 0xffff);
        Ts[d0 + 1][col] = (ushort)(u.x >> 16);
        Ts[d0 + 2][col] = (ushort)(u.y & 0xffff);
        Ts[d0 + 3][col] = (ushort)(u.y >> 16);
        Ts[d0 + 4][col] = (ushort)(u.z & 0xffff);
        Ts[d0 + 5][col] = (ushort)(u.z >> 16);
        Ts[d0 + 6][col] = (ushort)(u.w & 0xffff);
        Ts[d0 + 7][col] = (ushort)(u.w >> 16);
    }
    __syncthreads();
    #pragma unroll
    for (int i = 0; i < 2; ++i) {
        int cid = i * 256 + threadIdx.x;
        int d = cid >> 4, ch = cid & 15;
        uint4 o = *(const uint4*)&Ts[d][ch * 8];
        *(uint4*)(VTI + ((size_t)bh * HD_ + d) * S_ + sblk + ch * 8) = o;
    }
}

// ---------------------------------------------------------------------------
// Flash attention v5: 32 q/wave, swapped QK^T, no-max softmax, and K/V staged
// ONCE per block into double-buffered LDS via global_load_lds (2 gloads/wave/
// round; 4x less VMEM than v4). Chunk layouts make every fragment read a
// ds_read_b128 at addr = const + lane*16 (conflict-free):
//   K chunk (j*64 + g*16 + ll) <- K row 16j+ll, col g*8
//   V chunk ((dh*2+ch)*64 + g*16 + ll) <- Vt row dh*16+ll, col ch*32+g*8
// One __syncthreads per round (implicit vmcnt drain covers prior-round stage).
// ---------------------------------------------------------------------------
__global__ __launch_bounds__(256) void attn_kernel(
    const ushort* __restrict__ XNB, const ushort* __restrict__ VTI,
    float* __restrict__ X)
{
    __shared__ ushort Kl[2][2048];
    __shared__ ushort Vl[2][2048];

    const int bi = blockIdx.x;
    const int xcd = bi & 7, m = bi >> 3;          // m in [0,128)
    const int bh = xcd * 16 + (m >> 3);           // 16 bh per XCD
    const int bx = m & 7;                         // q-block (of 128) within bh
    const int b = bh >> 3, h = bh & 7;

    const ushort* __restrict__ base = XNB + (size_t)bh * (S_ * HD_);
    const ushort* __restrict__ vbase = VTI + (size_t)bh * (HD_ * S_);
    const int tid = threadIdx.x;
    const int w = tid >> 6, l = tid & 63, g = l >> 4, ll = l & 15;
    const int q0 = bx * 128 + w * 32;
    const int qgA = q0 + ll, qgB = q0 + 16 + ll;
    const int xq = q0 >> 5;                       // wave-constant
    const int yqA = ll, yqB = 16 + ll;

    const float C1 = SCALE_ * LOG2E_;
    frag qfA = *(const frag*)(base + (size_t)qgA * HD_ + g * 8);
    frag qfB = *(const frag*)(base + (size_t)qgB * HD_ + g * 8);
    #pragma unroll
    for (int i = 0; i < 8; ++i) {
        float fa = __builtin_bit_cast(float, ((uint)(ushort)qfA[i]) << 16);
        float fb = __builtin_bit_cast(float, ((uint)(ushort)qfB[i]) << 16);
        qfA[i] = (short)bf16b(fa * C1);
        qfB[i] = (short)bf16b(fb * C1);
    }

    const float slr = -exp2f(-(0.5f + (float)h)) * LOG2E_;
    const float sll = -exp2f(-(1.0f + (float)h)) * LOG2E_;
    const int itb = 2 * bx + (w >> 1);            // this wave's boundary round

    // delta = ll - (4g + r): dabs=|d|, d16m=16-d, d16p=16+d (round-constant)
    float dabs[4], d16m[4], d16p[4];
    #pragma unroll
    for (int r = 0; r < 4; ++r) {
        int del = ll - 4 * g - r;
        dabs[r] = (float)abs(del);
        d16m[r] = (float)(16 - del);
        d16p[r] = (float)(16 + del);
    }

    f32x4 o0A = {0,0,0,0}, o1A = {0,0,0,0}, osA = {0,0,0,0};
    f32x4 o0B = {0,0,0,0}, o1B = {0,0,0,0}, osB = {0,0,0,0};
    const f32x4 zc = {0,0,0,0};
    const short one_s = (short)0x3F80;
    const frag ones = { one_s, one_s, one_s, one_s, one_s, one_s, one_s, one_s };

    // staging roles (per lane): wave w stages K rows 16w+ll (col g*8) and
    // V rows (w>>1)*16+ll (col (w&1)*32+g*8); dest = linear chunk w*64+l.
    const ushort* ksrc = base  + (size_t)(16 * w + ll) * HD_ + g * 8;
    const ushort* vsrc = vbase + (size_t)((w >> 1) * 16 + ll) * S_ + (w & 1) * 32 + g * 8;
    const int dst = (w * 64 + l) * 8;

#define STAGE(NB, TILE)                                                       \
    gload16(ksrc + (size_t)(TILE) * 64 * HD_, &Kl[NB][dst]);                  \
    gload16(vsrc + (TILE) * 64,               &Vl[NB][dst]);

    STAGE(0, 0)
    __syncthreads();

#define EXACTR(r)                                                             \
  { int t0 = tb + 4 * g + (r);                                                \
    { int tg = t0;      int xt = tg >> 5, yt = tg & 31;                       \
      eA0[r] = exp2_raw(fmaf((tg > qgA) ? slr : sll,                          \
               (float)(abs(xq - xt) + abs(yqA - yt)), sa0[r]));               \
      eB0[r] = exp2_raw(fmaf((tg > qgB) ? slr : sll,                          \
               (float)(abs(xq - xt) + abs(yqB - yt)), sb0[r])); }             \
    { int tg = t0 + 16; int xt = tg >> 5, yt = tg & 31;                       \
      eA1[r] = exp2_raw(fmaf((tg > qgA) ? slr : sll,                          \
               (float)(abs(xq - xt) + abs(yqA - yt)), sa1[r]));               \
      eB1[r] = exp2_raw(fmaf((tg > qgB) ? slr : sll,                          \
               (float)(abs(xq - xt) + abs(yqB - yt)), sb1[r])); }             \
    { int tg = t0 + 32; int xt = tg >> 5, yt = tg & 31;                       \
      eA2[r] = exp2_raw(fmaf((tg > qgA) ? slr : sll,                          \
               (float)(abs(xq - xt) + abs(yqA - yt)), sa2[r]));               \
      eB2[r] = exp2_raw(fmaf((tg > qgB) ? slr : sll,                          \
               (float)(abs(xq - xt) + abs(yqB - yt)), sb2[r])); }             \
    { int tg = t0 + 48; int xt = tg >> 5, yt = tg & 31;                       \
      eA3[r] = exp2_raw(fmaf((tg > qgA) ? slr : sll,                          \
               (float)(abs(xq - xt) + abs(yqA - yt)), sa3[r]));               \
      eB3[r] = exp2_raw(fmaf((tg > qgB) ? slr : sll,                          \
               (float)(abs(xq - xt) + abs(yqB - yt)), sb3[r])); } }

#define FASTR(r)                                                              \
    eA0[r] = exp2_raw(fmaf(sl, dabs[r] + ax0, sa0[r]));                       \
    eA1[r] = exp2_raw(fmaf(sl, d16m[r] + ax0, sa1[r]));                       \
    eA2[r] = exp2_raw(fmaf(sl, dabs[r] + ax1, sa2[r]));                       \
    eA3[r] = exp2_raw(fmaf(sl, d16m[r] + ax1, sa3[r]));                       \
    eB0[r] = exp2_raw(fmaf(sl, d16p[r] + ax0, sb0[r]));                       \
    eB1[r] = exp2_raw(fmaf(sl, dabs[r] + ax0, sb1[r]));                       \
    eB2[r] = exp2_raw(fmaf(sl, d16p[r] + ax1, sb2[r]));                       \
    eB3[r] = exp2_raw(fmaf(sl, dabs[r] + ax1, sb3[r]));

    for (int it = 0; it < 16; ++it) {
        const int cur = it & 1, nxt = cur ^ 1;
        const int tb = it * 64;
        STAGE(nxt, (it + 1) & 15)           // prefetch next tile (last is redundant)

        frag K0 = *(const frag*)&Kl[cur][l * 8];
        frag K1 = *(const frag*)&Kl[cur][512 + l * 8];
        frag K2 = *(const frag*)&Kl[cur][1024 + l * 8];
        frag K3 = *(const frag*)&Kl[cur][1536 + l * 8];
        frag V0 = *(const frag*)&Vl[cur][l * 8];
        frag V2 = *(const frag*)&Vl[cur][512 + l * 8];
        frag V1 = *(const frag*)&Vl[cur][1024 + l * 8];
        frag V3 = *(const frag*)&Vl[cur][1536 + l * 8];

        f32x4 sa0 = MFMA(K0, qfA, zc);
        f32x4 sa1 = MFMA(K1, qfA, zc);
        f32x4 sa2 = MFMA(K2, qfA, zc);
        f32x4 sa3 = MFMA(K3, qfA, zc);
        f32x4 sb0 = MFMA(K0, qfB, zc);
        f32x4 sb1 = MFMA(K1, qfB, zc);
        f32x4 sb2 = MFMA(K2, qfB, zc);
        f32x4 sb3 = MFMA(K3, qfB, zc);

        f32x4 eA0, eA1, eA2, eA3, eB0, eB1, eB2, eB3;
        if (it == itb) {
            EXACTR(0) EXACTR(1) EXACTR(2) EXACTR(3)
        } else {
            const float sl = (it > itb) ? slr : sll;
            const float ax0 = (float)abs(xq - 2 * it);
            const float ax1 = (float)abs(xq - 2 * it - 1);
            FASTR(0) FASTR(1) FASTR(2) FASTR(3)
        }
        uint4 pa0 = { cvt_pk_bf16(eA0[0], eA0[1]), cvt_pk_bf16(eA0[2], eA0[3]),
                      cvt_pk_bf16(eA2[0], eA2[1]), cvt_pk_bf16(eA2[2], eA2[3]) };
        uint4 pa1 = { cvt_pk_bf16(eA1[0], eA1[1]), cvt_pk_bf16(eA1[2], eA1[3]),
                      cvt_pk_bf16(eA3[0], eA3[1]), cvt_pk_bf16(eA3[2], eA3[3]) };
        uint4 pb0 = { cvt_pk_bf16(eB0[0], eB0[1]), cvt_pk_bf16(eB0[2], eB0[3]),
                      cvt_pk_bf16(eB2[0], eB2[1]), cvt_pk_bf16(eB2[2], eB2[3]) };
        uint4 pb1 = { cvt_pk_bf16(eB1[0], eB1[1]), cvt_pk_bf16(eB1[2], eB1[3]),
                      cvt_pk_bf16(eB3[0], eB3[1]), cvt_pk_bf16(eB3[2], eB3[3]) };
        frag pfA0 = __builtin_bit_cast(frag, pa0);
        frag pfA1 = __builtin_bit_cast(frag, pa1);
        frag pfB0 = __builtin_bit_cast(frag, pb0);
        frag pfB1 = __builtin_bit_cast(frag, pb1);

        o0A = MFMA(pfA0, V0, o0A);  o1A = MFMA(pfA0, V1, o1A);
        osA = MFMA(pfA0, ones, osA);
        o0A = MFMA(pfA1, V2, o0A);  o1A = MFMA(pfA1, V3, o1A);
        osA = MFMA(pfA1, ones, osA);
        o0B = MFMA(pfB0, V0, o0B);  o1B = MFMA(pfB0, V1, o1B);
        osB = MFMA(pfB0, ones, osB);
        o0B = MFMA(pfB1, V2, o0B);  o1B = MFMA(pfB1, V3, o1B);
        osB = MFMA(pfB1, ones, osB);

        __syncthreads();   // drains vmcnt (stage complete) + all waves done with cur
    }
#undef STAGE
#undef FASTR
#undef EXACTR

    #pragma unroll
    for (int r = 0; r < 4; ++r) {
        float invA = 1.0f / osA[r];
        float invB = 1.0f / osB[r];
        float* xpA = X + ((size_t)(b * S_ + q0 + g * 4 + r)) * D_ + h * HD_;
        float* xpB = X + ((size_t)(b * S_ + q0 + 16 + g * 4 + r)) * D_ + h * HD_;
        xpA[ll]      += o0A[r] * invA;
        xpA[16 + ll] += o1A[r] * invA;
        xpB[ll]      += o0B[r] * invB;
        xpB[16 + ll] += o1B[r] * invB;
    }
}

// ---------------------------------------------------------------------------
// GEMM1: H[16384,1024] = GELU(A[16384,256]_bf16 @ W^T[1024,256] + b1), bf16 out
// ---------------------------------------------------------------------------
__global__ __launch_bounds__(256) void gemm1_kernel(
    const ushort* __restrict__ A, const ushort* __restrict__ Bt,
    const float* __restrict__ bias, ushort* __restrict__ Hout)
{
    __shared__ ushort As[128 * 32];
    __shared__ ushort Bs[128 * 32];
    const int tid = threadIdx.x;
    const int w = tid >> 6, l = tid & 63, g = l >> 4, ll = l & 15;
    const int wm = w >> 1, wn = w & 1;
    const int row0 = blockIdx.y * 128, col0 = blockIdx.x * 128;

    const int srow = w * 32 + (l >> 2);
    const int scol = (l & 3) * 8;
    const ushort* ga = A  + (size_t)(row0 + srow) * 256 + scol;
    const ushort* gb = Bt + (size_t)(col0 + srow) * 256 + scol;
    ushort* lA = &As[w * 1024 + l * 8];
    ushort* lB = &Bs[w * 1024 + l * 8];

    f32x4 acc[4][4] = {};
    for (int k0 = 0; k0 < 256; k0 += 32) {
        __syncthreads();
        gload16(ga + k0,            lA);
        gload16(ga + k0 + 16 * 256, lA + 512);
        gload16(gb + k0,            lB);
        gload16(gb + k0 + 16 * 256, lB + 512);
        __syncthreads();
        frag af[4], bfr[4];
        #pragma unroll
        for (int mb = 0; mb < 4; ++mb)
            af[mb] = *(const frag*)&As[(wm * 64 + mb * 16 + ll) * 32 + g * 8];
        #pragma unroll
        for (int nb = 0; nb < 4; ++nb)
            bfr[nb] = *(const frag*)&Bs[(wn * 64 + nb * 16 + ll) * 32 + g * 8];
        #pragma unroll
        for (int mb = 0; mb < 4; ++mb)
            #pragma unroll
            for (int nb = 0; nb < 4; ++nb)
                acc[mb][nb] = MFMA(af[mb], bfr[nb], acc[mb][nb]);
    }

    #pragma unroll
    for (int nb = 0; nb < 4; ++nb) {
        int col = col0 + wn * 64 + nb * 16 + ll;
        float bv = bias[col];
        #pragma unroll
        for (int mb = 0; mb < 4; ++mb) {
            #pragma unroll
            for (int r = 0; r < 4; ++r) {
                int row = row0 + wm * 64 + mb * 16 + g * 4 + r;
                float v = acc[mb][nb][r] + bv;
                float u2 = 1.5957691216f * v + 0.0713548162f * (v * v * v);
                float e = exp2_raw(u2 * LOG2E_);
                float rr = __builtin_amdgcn_rcpf(e + 1.0f);
                float gl = v - v * rr;
                Hout[(size_t)row * 1024 + col] = bf16b(gl);
            }
        }
    }
}

// ---------------------------------------------------------------------------
// GEMM2: X[16384,256] += A[16384,1024]_bf16 @ W^T[256,1024] + b2
// 128(M)x64(N) tile, 4 waves, K=1024. grid (4, 128).
// ---------------------------------------------------------------------------
__global__ __launch_bounds__(256) void gemm2_kernel(
    const ushort* __restrict__ A, const ushort* __restrict__ Bt,
    const float* __restrict__ bias, float* __restrict__ X)
{
    __shared__ ushort As[128 * 32];
    __shared__ ushort Bs[64 * 32];
    const int tid = threadIdx.x;
    const int w = tid >> 6, l = tid & 63, g = l >> 4, ll = l & 15;
    const int row0 = blockIdx.y * 128, col0 = blockIdx.x * 64;

    const int srow = w * 32 + (l >> 2);
    const int scol = (l & 3) * 8;
    const ushort* ga = A  + (size_t)(row0 + srow) * 1024 + scol;
    const ushort* gb = Bt + (size_t)(col0 + w * 16 + (l >> 2)) * 1024 + scol;
    ushort* lA = &As[w * 1024 + l * 8];
    ushort* lB = &Bs[w * 512 + l * 8];

    f32x4 acc[2][4] = {};
    for (int k0 = 0; k0 < 1024; k0 += 32) {
        __syncthreads();
        gload16(ga + k0,             lA);
        gload16(ga + k0 + 16 * 1024, lA + 512);
        gload16(gb + k0,             lB);
        __syncthreads();
        frag af[2], bfr[4];
        #pragma unroll
        for (int mb = 0; mb < 2; ++mb)
            af[mb] = *(const frag*)&As[(w * 32 + mb * 16 + ll) * 32 + g * 8];
        #pragma unroll
        for (int nb = 0; nb < 4; ++nb)
            bfr[nb] = *(const frag*)&Bs[(nb * 16 + ll) * 32 + g * 8];
        #pragma unroll
        for (int mb = 0; mb < 2; ++mb)
            #pragma unroll
            for (int nb = 0; nb < 4; ++nb)
                acc[mb][nb] = MFMA(af[mb], bfr[nb], acc[mb][nb]);
    }

    #pragma unroll
    for (int nb = 0; nb < 4; ++nb) {
        int col = col0 + nb * 16 + ll;
        float bv = bias[col];
        #pragma unroll
        for (int mb = 0; mb < 2; ++mb) {
            #pragma unroll
            for (int r = 0; r < 4; ++r) {
                int row = row0 + w * 32 + mb * 16 + g * 4 + r;
                float* xp = X + (size_t)row * 256 + col;
                *xp += acc[mb][nb][r] + bv;
            }
        }
    }
}

// ---------------------------------------------------------------------------
extern "C" void kernel_launch(void* const* d_in, const int* in_sizes, int n_in,
                              void* d_out, int out_size, void* d_ws, size_t ws_size,
                              hipStream_t stream)
{
    const int*   tokens  = (const int*)d_in[0];
    const int*   pos_ids = (const int*)d_in[1];
    const float* emb     = (const float*)d_in[2];
    const float* iw      = (const float*)d_in[3];
    const float* pw      = (const float*)d_in[4];
    const float* ln1w    = (const float*)d_in[5];
    const float* ln1b    = (const float*)d_in[6];
    const float* ln2w    = (const float*)d_in[7];
    const float* ln2b    = (const float*)d_in[8];
    const float* w1      = (const float*)d_in[9];
    const float* b1      = (const float*)d_in[10];
    const float* w2      = (const float*)d_in[11];
    const float* b2      = (const float*)d_in[12];
    const float* lnfw    = (const float*)d_in[13];
    const float* lnfb    = (const float*)d_in[14];

    float* x = (float*)d_out;                    // [B,S,D] f32 residual stream
    char* ws = (char*)d_ws;
    ushort* xn   = (ushort*)ws;                  // 8,388,608 B
    ushort* vti  = (ushort*)(ws + 8388608);      // 8,388,608 B
    ushort* hbuf = (ushort*)(ws + 16777216);     // 33,554,432 B
    ushort* w1t  = (ushort*)(ws + 50331648);     // 3,145,728 B  [L][1024][256]
    ushort* w2t  = (ushort*)(ws + 53477376);     // 3,145,728 B  [L][256][1024]

    wtr_kernel<<<dim3(32, 8, L_), 256, 0, stream>>>(w1, w1t, 256, 1024);
    wtr_kernel<<<dim3(8, 32, L_), 256, 0, stream>>>(w2, w2t, 1024, 256);

    embed_kernel<<<B_ * S_, 256, 0, stream>>>(tokens, pos_ids, emb, iw, pw, x);

    for (int l = 0; l < L_; l++) {
        ln_kernel<1><<<(B_ * S_) / 4, 256, 0, stream>>>(x, ln1w + l * D_, ln1b + l * D_, xn);
        vtr_kernel<<<dim3(S_ / 128, B_ * H_), 256, 0, stream>>>(xn, vti);
        attn_kernel<<<(S_ / 128) * B_ * H_, 256, 0, stream>>>(xn, vti, x);
        ln_kernel<2><<<(B_ * S_) / 4, 256, 0, stream>>>(x, ln2w + l * D_, ln2b + l * D_, xn);
        gemm1_kernel<<<dim3(H2_ / 128, (B_ * S_) / 128), 256, 0, stream>>>(
            xn, w1t + (size_t)l * D_ * H2_, b1 + (size_t)l * H2_, hbuf);
        gemm2_kernel<<<dim3(D_ / 64, (B_ * S_) / 128), 256, 0, stream>>>(
            hbuf, w2t + (size_t)l * H2_ * D_, b2 + (size_t)l * D_, x);
    }
    ln_kernel<0><<<(B_ * S_) / 4, 256, 0, stream>>>(x, lnfw, lnfb, x);
}